// Round 13
// baseline (502.023 us; speedup 1.0000x reference)
//
#include <hip/hip_runtime.h>
#include <hip/hip_fp16.h>
#include <math.h>

#define N_NODES 100000
#define H_DIM 64
#define G_GRAPHS 512
#define NEG_SLOPE 0.2f

// bucketed CSR-build params
#define BSHIFT 9                         // 512 nodes per bucket
#define NBKT ((N_NODES + (1 << BSHIFT) - 1) >> BSHIFT)   // 196
#define CHUNK_E 4096                     // edges per partition block (16/thread)

#define DEG_CAP 128                      // staged edges per node (Poisson(16) max ~45)

// packed edge: src in bits [0,17), in-bucket dst in bits [17,26)
#define PK_SRC(v)  ((v) & 0x1FFFF)
#define PK_LD(v)   ((v) >> 17)

// ---------------------------------------------------------------------------
// CSR build, bucket-first: no per-edge global atomics anywhere.
// ---------------------------------------------------------------------------

__global__ __launch_bounds__(256) void bucket_hist_kernel(const int* __restrict__ dst,
                                                          int* __restrict__ bcount, int E) {
    __shared__ int lh[NBKT];
    int t = threadIdx.x;
    for (int i = t; i < NBKT; i += 256) lh[i] = 0;
    __syncthreads();
    int base = blockIdx.x * CHUNK_E;
#pragma unroll
    for (int k = 0; k < 16; ++k) {
        int e = base + k * 256 + t;
        if (e < E) atomicAdd(&lh[dst[e] >> BSHIFT], 1);
    }
    __syncthreads();
    for (int i = t; i < NBKT; i += 256) {
        int c = lh[i];
        if (c) atomicAdd(&bcount[i], c);
    }
}

__global__ __launch_bounds__(256) void bucket_scan_kernel(const int* __restrict__ bcount,
                                                          int* __restrict__ bbase,
                                                          int* __restrict__ bfill,
                                                          int* __restrict__ off, int n) {
    __shared__ int sm[256];
    int t = threadIdx.x;
    sm[t] = (t < NBKT) ? bcount[t] : 0;
    __syncthreads();
    for (int d = 1; d < 256; d <<= 1) {
        int v = (t >= d) ? sm[t - d] : 0;
        __syncthreads();
        sm[t] += v;
        __syncthreads();
    }
    if (t < NBKT) {
        int ex = (t == 0) ? 0 : sm[t - 1];
        bbase[t] = ex;
        bfill[t] = ex;
    }
    if (t == 0) {
        bbase[NBKT] = sm[255];       // = E
        off[n] = sm[255];
    }
}

__global__ __launch_bounds__(256) void partition_kernel(const int* __restrict__ src,
                                                        const int* __restrict__ dst,
                                                        int* __restrict__ bfill,
                                                        int* __restrict__ ebuck, int E) {
    __shared__ int lh[NBKT];
    __shared__ int lbase[NBKT];
    int t = threadIdx.x;
    int base = blockIdx.x * CHUNK_E;
    for (int i = t; i < NBKT; i += 256) lh[i] = 0;
    __syncthreads();

    int pk[16], bk[16];
#pragma unroll
    for (int k = 0; k < 16; ++k) {
        int e = base + k * 256 + t;
        if (e < E) {
            int s = src[e];
            int d = dst[e];
            bk[k] = d >> BSHIFT;
            pk[k] = s | ((d & ((1 << BSHIFT) - 1)) << 17);
            atomicAdd(&lh[bk[k]], 1);
        } else {
            bk[k] = -1;
        }
    }
    __syncthreads();
    for (int i = t; i < NBKT; i += 256) {
        int c = lh[i];
        lbase[i] = c ? atomicAdd(&bfill[i], c) : 0;
        lh[i] = 0;
    }
    __syncthreads();
#pragma unroll
    for (int k = 0; k < 16; ++k) {
        if (bk[k] >= 0) {
            int r = atomicAdd(&lh[bk[k]], 1);
            ebuck[lbase[bk[k]] + r] = pk[k];
        }
    }
}

__global__ __launch_bounds__(256) void bucket_csr_kernel(const int* __restrict__ ebuck,
                                                         const int* __restrict__ bbase,
                                                         int* __restrict__ off,
                                                         int* __restrict__ esrc, int n) {
    __shared__ int cnt[512];
    __shared__ int loff[512];
    __shared__ int sm[256];
    int b = blockIdx.x;
    int t = threadIdx.x;
    int ebeg = bbase[b];
    int eend = bbase[b + 1];
    int nbeg = b << BSHIFT;
    int nloc = n - nbeg; if (nloc > 512) nloc = 512;

    cnt[t] = 0; cnt[t + 256] = 0;
    __syncthreads();
    for (int e = ebeg + t; e < eend; e += 256) {
        atomicAdd(&cnt[PK_LD(ebuck[e])], 1);
    }
    __syncthreads();
    int c0 = cnt[2 * t], c1 = cnt[2 * t + 1];
    sm[t] = c0 + c1;
    __syncthreads();
    for (int d = 1; d < 256; d <<= 1) {
        int v = (t >= d) ? sm[t - d] : 0;
        __syncthreads();
        sm[t] += v;
        __syncthreads();
    }
    int basep = (t == 0) ? 0 : sm[t - 1];
    loff[2 * t] = basep;
    loff[2 * t + 1] = basep + c0;
    cnt[2 * t] = 0; cnt[2 * t + 1] = 0;
    __syncthreads();
    for (int i = t; i < nloc; i += 256) off[nbeg + i] = ebeg + loff[i];
    for (int e = ebeg + t; e < eend; e += 256) {
        int v = ebuck[e];
        int d = PK_LD(v);
        int r = atomicAdd(&cnt[d], 1);
        esrc[ebeg + loff[d] + r] = PK_SRC(v);
    }
}

// ---------------------------------------------------------------------------
// Layer-0 GEMM + logits (round-4/5 structure, fp32 x input, fp16 h output).
// ---------------------------------------------------------------------------
template <int FIN, int FINP, int XSTR>
__global__ __launch_bounds__(256) void gemm_tile_kernel(
        const float* __restrict__ act, const float* __restrict__ W,
        const float* __restrict__ a_s, const float* __restrict__ a_d,
        __half* __restrict__ h16g,
        float* __restrict__ ls, float* __restrict__ ld,
        int n) {
    __shared__ float sx[128 * XSTR];
    __shared__ float sw[FINP * 64];
    int t = threadIdx.x;
    int tb = blockIdx.x * 128;
    int nrow = n - tb; if (nrow > 128) nrow = 128;

    {
        const float4* Wv = (const float4*)W;
        float4* swv = (float4*)sw;
        for (int i = t; i < FINP * 16; i += 256) {
            int k = i >> 4;
            swv[i] = (k < FIN) ? Wv[i] : make_float4(0.0f, 0.0f, 0.0f, 0.0f);
        }
    }
    {
        // scalar staging for unaligned FIN-float rows; pad cols [FIN,FINP) to 0
        int c = t & 15;
        for (int r = t >> 4; r < 128; r += 16) {
            float v = 0.0f;
            if (r < nrow && c < FIN) v = act[(size_t)(tb + r) * FIN + c];
            sx[r * XSTR + c] = v;
        }
    }
    __syncthreads();

    int f4 = t & 15;
    int ng = t >> 4;          // [0, 16)

    float4 acc[8];
#pragma unroll
    for (int i = 0; i < 8; ++i) acc[i] = make_float4(0.0f, 0.0f, 0.0f, 0.0f);

    for (int k4 = 0; k4 < FINP; k4 += 4) {
        float4 w0 = *(const float4*)(sw + (k4 + 0) * 64 + f4 * 4);
        float4 w1 = *(const float4*)(sw + (k4 + 1) * 64 + f4 * 4);
        float4 w2 = *(const float4*)(sw + (k4 + 2) * 64 + f4 * 4);
        float4 w3 = *(const float4*)(sw + (k4 + 3) * 64 + f4 * 4);
#pragma unroll
        for (int i = 0; i < 8; ++i) {
            float4 xv = *(const float4*)(sx + (ng + 16 * i) * XSTR + k4);
            acc[i].x = fmaf(xv.x, w0.x, acc[i].x);
            acc[i].y = fmaf(xv.x, w0.y, acc[i].y);
            acc[i].z = fmaf(xv.x, w0.z, acc[i].z);
            acc[i].w = fmaf(xv.x, w0.w, acc[i].w);
            acc[i].x = fmaf(xv.y, w1.x, acc[i].x);
            acc[i].y = fmaf(xv.y, w1.y, acc[i].y);
            acc[i].z = fmaf(xv.y, w1.z, acc[i].z);
            acc[i].w = fmaf(xv.y, w1.w, acc[i].w);
            acc[i].x = fmaf(xv.z, w2.x, acc[i].x);
            acc[i].y = fmaf(xv.z, w2.y, acc[i].y);
            acc[i].z = fmaf(xv.z, w2.z, acc[i].z);
            acc[i].w = fmaf(xv.z, w2.w, acc[i].w);
            acc[i].x = fmaf(xv.w, w3.x, acc[i].x);
            acc[i].y = fmaf(xv.w, w3.y, acc[i].y);
            acc[i].z = fmaf(xv.w, w3.z, acc[i].z);
            acc[i].w = fmaf(xv.w, w3.w, acc[i].w);
        }
    }

    float4 as4 = *(const float4*)(a_s + f4 * 4);
    float4 ad4 = *(const float4*)(a_d + f4 * 4);
#pragma unroll
    for (int i = 0; i < 8; ++i) {
        int r = ng + 16 * i;
        if (r < nrow) {
            int node = tb + r;
            __half2 plo = __floats2half2_rn(acc[i].x, acc[i].y);
            __half2 phi = __floats2half2_rn(acc[i].z, acc[i].w);
            uint2 pk;
            pk.x = *reinterpret_cast<unsigned*>(&plo);
            pk.y = *reinterpret_cast<unsigned*>(&phi);
            *reinterpret_cast<uint2*>(h16g + (size_t)node * 64 + f4 * 4) = pk;
            float vs = acc[i].x * as4.x + acc[i].y * as4.y +
                       acc[i].z * as4.z + acc[i].w * as4.w;
            float vd = acc[i].x * ad4.x + acc[i].y * ad4.y +
                       acc[i].z * ad4.z + acc[i].w * ad4.w;
            vs += __shfl_xor(vs, 1, 64); vd += __shfl_xor(vd, 1, 64);
            vs += __shfl_xor(vs, 2, 64); vd += __shfl_xor(vd, 2, 64);
            vs += __shfl_xor(vs, 4, 64); vd += __shfl_xor(vd, 4, 64);
            vs += __shfl_xor(vs, 8, 64); vd += __shfl_xor(vd, 8, 64);
            if (f4 == 0) { ls[node] = vs; ld[node] = vd; }
        }
    }
}

// ---------------------------------------------------------------------------
// FUSED: gat(layer l) + gemm(layer l+1) + logits(layer l+1).
// gat part = round-5 v3 structure (16-lane group per node, LDS-staged (src,p),
// 4-wide fp16 gather). The resulting ELU activation o (float4/lane) is fed
// straight into the next layer's GEMM row: o broadcast via intra-group shfl,
// W(l+1) staged in LDS. Writes h16_out row + next-layer ls/ld. No activation
// tensor ever hits memory. Double-buffered (in != out).
// ---------------------------------------------------------------------------
__global__ __launch_bounds__(256) void gat_gemm_kernel(
        const __half* __restrict__ h16_in, const float* __restrict__ ls_in,
        const float* __restrict__ ld_in, const int* __restrict__ off,
        const int* __restrict__ esrc, const float* __restrict__ bias,
        const float* __restrict__ Wn, const float* __restrict__ asn,
        const float* __restrict__ adn,
        __half* __restrict__ h16_out, float* __restrict__ ls_out,
        float* __restrict__ ld_out, int n) {
    __shared__ float sw[64 * 64];            // 16 KB: W(l+1)
    __shared__ int2 smq[16 * DEG_CAP];       // 16 KB: (src, ls->p) per group
    int t = threadIdx.x;
    // stage W with ALL threads (before any early return)
    {
        const float4* Wv = (const float4*)Wn;
        float4* swv = (float4*)sw;
        for (int i = t; i < 64 * 16; i += 256) swv[i] = Wv[i];
    }
    __syncthreads();   // no barriers after this point (intra-group ops only)

    int lane = t & 63;
    int fl = t & 15;
    int g = t >> 4;
    int node = blockIdx.x * 16 + g;
    if (node >= n) return;
    int2* sq = smq + g * DEG_CAP;
    int fl4 = fl * 4;

    int jb = off[node];
    int je = off[node + 1];
    int deg = je - jb;
    int degc = (deg < DEG_CAP) ? deg : DEG_CAP;
    float ldv = ld_in[node];
    float lself = ls_in[node];

    // pass 1: gather ls, stage, running max (leaky is monotone)
    float mm = lself;
    for (int c = fl; c < degc; c += 16) {
        int s = esrc[jb + c];
        float v = ls_in[s];
        sq[c] = make_int2(s, __float_as_int(v));
        mm = fmaxf(mm, v);
    }
    for (int c = degc + fl; c < deg; c += 16) {
        mm = fmaxf(mm, ls_in[esrc[jb + c]]);
    }
    mm = fmaxf(mm, __shfl_xor(mm, 8, 64));
    mm = fmaxf(mm, __shfl_xor(mm, 4, 64));
    mm = fmaxf(mm, __shfl_xor(mm, 2, 64));
    mm = fmaxf(mm, __shfl_xor(mm, 1, 64));
    float mraw = mm + ldv;
    float m = (mraw >= 0.0f) ? mraw : NEG_SLOPE * mraw;

    // pass 2: ls -> p in LDS, lane-partial den
    float denl = 0.0f;
    for (int c = fl; c < degc; c += 16) {
        float e = __int_as_float(sq[c].y) + ldv;
        e = (e >= 0.0f) ? e : NEG_SLOPE * e;
        float p = __expf(e - m);
        sq[c].y = __float_as_int(p);
        denl += p;
    }
    int degc4 = (degc + 3) & ~3;
    if (fl < degc4 - degc) sq[degc + fl] = make_int2(node, 0);

    denl += __shfl_xor(denl, 8, 64);
    denl += __shfl_xor(denl, 4, 64);
    denl += __shfl_xor(denl, 2, 64);
    denl += __shfl_xor(denl, 1, 64);

    // self row early
    uint2 qs = *reinterpret_cast<const uint2*>(h16_in + (size_t)node * 64 + fl4);
    float2 sa = __half22float2(*reinterpret_cast<__half2*>(&qs.x));
    float2 sb = __half22float2(*reinterpret_cast<__half2*>(&qs.y));

    // gather loop: 4 independent 128B fp16 row loads in flight per group
    float4 acc = make_float4(0.0f, 0.0f, 0.0f, 0.0f);
    for (int c = 0; c < degc4; c += 4) {
        int2 e0 = sq[c + 0];
        int2 e1 = sq[c + 1];
        int2 e2 = sq[c + 2];
        int2 e3 = sq[c + 3];
        uint2 q0 = *reinterpret_cast<const uint2*>(h16_in + (size_t)e0.x * 64 + fl4);
        uint2 q1 = *reinterpret_cast<const uint2*>(h16_in + (size_t)e1.x * 64 + fl4);
        uint2 q2 = *reinterpret_cast<const uint2*>(h16_in + (size_t)e2.x * 64 + fl4);
        uint2 q3 = *reinterpret_cast<const uint2*>(h16_in + (size_t)e3.x * 64 + fl4);
        float p0 = __int_as_float(e0.y), p1 = __int_as_float(e1.y);
        float p2 = __int_as_float(e2.y), p3 = __int_as_float(e3.y);
        float2 a0 = __half22float2(*reinterpret_cast<__half2*>(&q0.x));
        float2 b0 = __half22float2(*reinterpret_cast<__half2*>(&q0.y));
        float2 a1 = __half22float2(*reinterpret_cast<__half2*>(&q1.x));
        float2 b1 = __half22float2(*reinterpret_cast<__half2*>(&q1.y));
        float2 a2 = __half22float2(*reinterpret_cast<__half2*>(&q2.x));
        float2 b2 = __half22float2(*reinterpret_cast<__half2*>(&q2.y));
        float2 a3 = __half22float2(*reinterpret_cast<__half2*>(&q3.x));
        float2 b3 = __half22float2(*reinterpret_cast<__half2*>(&q3.y));
        acc.x = fmaf(p0, a0.x, acc.x); acc.y = fmaf(p0, a0.y, acc.y);
        acc.z = fmaf(p0, b0.x, acc.z); acc.w = fmaf(p0, b0.y, acc.w);
        acc.x = fmaf(p1, a1.x, acc.x); acc.y = fmaf(p1, a1.y, acc.y);
        acc.z = fmaf(p1, b1.x, acc.z); acc.w = fmaf(p1, b1.y, acc.w);
        acc.x = fmaf(p2, a2.x, acc.x); acc.y = fmaf(p2, a2.y, acc.y);
        acc.z = fmaf(p2, b2.x, acc.z); acc.w = fmaf(p2, b2.y, acc.w);
        acc.x = fmaf(p3, a3.x, acc.x); acc.y = fmaf(p3, a3.y, acc.y);
        acc.z = fmaf(p3, b3.x, acc.z); acc.w = fmaf(p3, b3.y, acc.w);
    }

    // overflow tail (deg > DEG_CAP, ~never)
    float den_of = 0.0f;
    for (int j = jb + DEG_CAP; j < je; ++j) {
        int s = esrc[j];
        float e = ls_in[s] + ldv;
        e = (e >= 0.0f) ? e : NEG_SLOPE * e;
        float p = __expf(e - m);
        den_of += p;
        uint2 qv = *reinterpret_cast<const uint2*>(h16_in + (size_t)s * 64 + fl4);
        float2 va = __half22float2(*reinterpret_cast<__half2*>(&qv.x));
        float2 vb = __half22float2(*reinterpret_cast<__half2*>(&qv.y));
        acc.x = fmaf(p, va.x, acc.x);
        acc.y = fmaf(p, va.y, acc.y);
        acc.z = fmaf(p, vb.x, acc.z);
        acc.w = fmaf(p, vb.y, acc.w);
    }

    // self loop
    float e0s = lself + ldv;
    e0s = (e0s >= 0.0f) ? e0s : NEG_SLOPE * e0s;
    float p0s = __expf(e0s - m);
    float den = denl + den_of + p0s;
    acc.x = fmaf(p0s, sa.x, acc.x);
    acc.y = fmaf(p0s, sa.y, acc.y);
    acc.z = fmaf(p0s, sb.x, acc.z);
    acc.w = fmaf(p0s, sb.y, acc.w);

    const float4 b4 = *(const float4*)(bias + fl4);
    float inv = 1.0f / den;
    float4 o;
    o.x = acc.x * inv + b4.x;
    o.y = acc.y * inv + b4.y;
    o.z = acc.z * inv + b4.z;
    o.w = acc.w * inv + b4.w;
    o.x = (o.x > 0.0f) ? o.x : expm1f(o.x);
    o.y = (o.y > 0.0f) ? o.y : expm1f(o.y);
    o.z = (o.z > 0.0f) ? o.z : expm1f(o.z);
    o.w = (o.w > 0.0f) ? o.w : expm1f(o.w);

    // --- fused next-layer GEMM row: hn[f] = sum_k o[k] * Wn[k][f] ---
    // o is distributed 4 elems/lane across the 16-lane group; broadcast via
    // intra-group shfl (src lane stays inside this group -> safe if other
    // groups in the wave exited).
    float4 ha = make_float4(0.0f, 0.0f, 0.0f, 0.0f);
    int gb = lane & 48;
#pragma unroll
    for (int kk = 0; kk < 16; ++kk) {
        float ox = __shfl(o.x, gb + kk, 64);
        float oy = __shfl(o.y, gb + kk, 64);
        float oz = __shfl(o.z, gb + kk, 64);
        float ow = __shfl(o.w, gb + kk, 64);
        const float4 w0 = *(const float4*)(sw + (4 * kk + 0) * 64 + fl4);
        const float4 w1 = *(const float4*)(sw + (4 * kk + 1) * 64 + fl4);
        const float4 w2 = *(const float4*)(sw + (4 * kk + 2) * 64 + fl4);
        const float4 w3 = *(const float4*)(sw + (4 * kk + 3) * 64 + fl4);
        ha.x = fmaf(ox, w0.x, ha.x); ha.y = fmaf(ox, w0.y, ha.y);
        ha.z = fmaf(ox, w0.z, ha.z); ha.w = fmaf(ox, w0.w, ha.w);
        ha.x = fmaf(oy, w1.x, ha.x); ha.y = fmaf(oy, w1.y, ha.y);
        ha.z = fmaf(oy, w1.z, ha.z); ha.w = fmaf(oy, w1.w, ha.w);
        ha.x = fmaf(oz, w2.x, ha.x); ha.y = fmaf(oz, w2.y, ha.y);
        ha.z = fmaf(oz, w2.z, ha.z); ha.w = fmaf(oz, w2.w, ha.w);
        ha.x = fmaf(ow, w3.x, ha.x); ha.y = fmaf(ow, w3.y, ha.y);
        ha.z = fmaf(ow, w3.z, ha.z); ha.w = fmaf(ow, w3.w, ha.w);
    }

    // store fp16 h row for next layer
    {
        __half2 plo = __floats2half2_rn(ha.x, ha.y);
        __half2 phi = __floats2half2_rn(ha.z, ha.w);
        uint2 pk;
        pk.x = *reinterpret_cast<unsigned*>(&plo);
        pk.y = *reinterpret_cast<unsigned*>(&phi);
        *reinterpret_cast<uint2*>(h16_out + (size_t)node * 64 + fl4) = pk;
    }
    // next-layer logits
    float4 as4 = *(const float4*)(asn + fl4);
    float4 ad4 = *(const float4*)(adn + fl4);
    float vs = ha.x * as4.x + ha.y * as4.y + ha.z * as4.z + ha.w * as4.w;
    float vd = ha.x * ad4.x + ha.y * ad4.y + ha.z * ad4.z + ha.w * ad4.w;
    vs += __shfl_xor(vs, 1, 64); vd += __shfl_xor(vd, 1, 64);
    vs += __shfl_xor(vs, 2, 64); vd += __shfl_xor(vd, 2, 64);
    vs += __shfl_xor(vs, 4, 64); vd += __shfl_xor(vd, 4, 64);
    vs += __shfl_xor(vs, 8, 64); vd += __shfl_xor(vd, 8, 64);
    if (fl == 0) { ls_out[node] = vs; ld_out[node] = vd; }
}

// ---------------------------------------------------------------------------
// Final-layer GAT (no fused gemm): fp16 gather, fp32 activation output.
// ---------------------------------------------------------------------------
__global__ __launch_bounds__(256) void gat_final_kernel(
        const __half* __restrict__ h16_in,
        const float* __restrict__ ls_in,
        const float* __restrict__ ld_in, const int* __restrict__ off,
        const int* __restrict__ esrc, const float* __restrict__ bias,
        float* __restrict__ hout, int n) {
    __shared__ int2 smq[16 * DEG_CAP];
    int t = threadIdx.x;
    int fl = t & 15;
    int g = t >> 4;
    int node = blockIdx.x * 16 + g;
    if (node >= n) return;
    int2* sq = smq + g * DEG_CAP;
    int fl4 = fl * 4;

    int jb = off[node];
    int je = off[node + 1];
    int deg = je - jb;
    int degc = (deg < DEG_CAP) ? deg : DEG_CAP;
    float ldv = ld_in[node];
    float lself = ls_in[node];

    float mm = lself;
    for (int c = fl; c < degc; c += 16) {
        int s = esrc[jb + c];
        float v = ls_in[s];
        sq[c] = make_int2(s, __float_as_int(v));
        mm = fmaxf(mm, v);
    }
    for (int c = degc + fl; c < deg; c += 16) {
        mm = fmaxf(mm, ls_in[esrc[jb + c]]);
    }
    mm = fmaxf(mm, __shfl_xor(mm, 8, 64));
    mm = fmaxf(mm, __shfl_xor(mm, 4, 64));
    mm = fmaxf(mm, __shfl_xor(mm, 2, 64));
    mm = fmaxf(mm, __shfl_xor(mm, 1, 64));
    float mraw = mm + ldv;
    float m = (mraw >= 0.0f) ? mraw : NEG_SLOPE * mraw;

    float denl = 0.0f;
    for (int c = fl; c < degc; c += 16) {
        float e = __int_as_float(sq[c].y) + ldv;
        e = (e >= 0.0f) ? e : NEG_SLOPE * e;
        float p = __expf(e - m);
        sq[c].y = __float_as_int(p);
        denl += p;
    }
    int degc4 = (degc + 3) & ~3;
    if (fl < degc4 - degc) sq[degc + fl] = make_int2(node, 0);

    denl += __shfl_xor(denl, 8, 64);
    denl += __shfl_xor(denl, 4, 64);
    denl += __shfl_xor(denl, 2, 64);
    denl += __shfl_xor(denl, 1, 64);

    uint2 qs = *reinterpret_cast<const uint2*>(h16_in + (size_t)node * 64 + fl4);
    float2 sa = __half22float2(*reinterpret_cast<__half2*>(&qs.x));
    float2 sb = __half22float2(*reinterpret_cast<__half2*>(&qs.y));

    float4 acc = make_float4(0.0f, 0.0f, 0.0f, 0.0f);
    for (int c = 0; c < degc4; c += 4) {
        int2 e0 = sq[c + 0];
        int2 e1 = sq[c + 1];
        int2 e2 = sq[c + 2];
        int2 e3 = sq[c + 3];
        uint2 q0 = *reinterpret_cast<const uint2*>(h16_in + (size_t)e0.x * 64 + fl4);
        uint2 q1 = *reinterpret_cast<const uint2*>(h16_in + (size_t)e1.x * 64 + fl4);
        uint2 q2 = *reinterpret_cast<const uint2*>(h16_in + (size_t)e2.x * 64 + fl4);
        uint2 q3 = *reinterpret_cast<const uint2*>(h16_in + (size_t)e3.x * 64 + fl4);
        float p0 = __int_as_float(e0.y), p1 = __int_as_float(e1.y);
        float p2 = __int_as_float(e2.y), p3 = __int_as_float(e3.y);
        float2 a0 = __half22float2(*reinterpret_cast<__half2*>(&q0.x));
        float2 b0 = __half22float2(*reinterpret_cast<__half2*>(&q0.y));
        float2 a1 = __half22float2(*reinterpret_cast<__half2*>(&q1.x));
        float2 b1 = __half22float2(*reinterpret_cast<__half2*>(&q1.y));
        float2 a2 = __half22float2(*reinterpret_cast<__half2*>(&q2.x));
        float2 b2 = __half22float2(*reinterpret_cast<__half2*>(&q2.y));
        float2 a3 = __half22float2(*reinterpret_cast<__half2*>(&q3.x));
        float2 b3 = __half22float2(*reinterpret_cast<__half2*>(&q3.y));
        acc.x = fmaf(p0, a0.x, acc.x); acc.y = fmaf(p0, a0.y, acc.y);
        acc.z = fmaf(p0, b0.x, acc.z); acc.w = fmaf(p0, b0.y, acc.w);
        acc.x = fmaf(p1, a1.x, acc.x); acc.y = fmaf(p1, a1.y, acc.y);
        acc.z = fmaf(p1, b1.x, acc.z); acc.w = fmaf(p1, b1.y, acc.w);
        acc.x = fmaf(p2, a2.x, acc.x); acc.y = fmaf(p2, a2.y, acc.y);
        acc.z = fmaf(p2, b2.x, acc.z); acc.w = fmaf(p2, b2.y, acc.w);
        acc.x = fmaf(p3, a3.x, acc.x); acc.y = fmaf(p3, a3.y, acc.y);
        acc.z = fmaf(p3, b3.x, acc.z); acc.w = fmaf(p3, b3.y, acc.w);
    }

    float den_of = 0.0f;
    for (int j = jb + DEG_CAP; j < je; ++j) {
        int s = esrc[j];
        float e = ls_in[s] + ldv;
        e = (e >= 0.0f) ? e : NEG_SLOPE * e;
        float p = __expf(e - m);
        den_of += p;
        uint2 qv = *reinterpret_cast<const uint2*>(h16_in + (size_t)s * 64 + fl4);
        float2 va = __half22float2(*reinterpret_cast<__half2*>(&qv.x));
        float2 vb = __half22float2(*reinterpret_cast<__half2*>(&qv.y));
        acc.x = fmaf(p, va.x, acc.x);
        acc.y = fmaf(p, va.y, acc.y);
        acc.z = fmaf(p, vb.x, acc.z);
        acc.w = fmaf(p, vb.y, acc.w);
    }

    float e0s = lself + ldv;
    e0s = (e0s >= 0.0f) ? e0s : NEG_SLOPE * e0s;
    float p0s = __expf(e0s - m);
    float den = denl + den_of + p0s;
    acc.x = fmaf(p0s, sa.x, acc.x);
    acc.y = fmaf(p0s, sa.y, acc.y);
    acc.z = fmaf(p0s, sb.x, acc.z);
    acc.w = fmaf(p0s, sb.y, acc.w);

    const float4 b4 = *(const float4*)(bias + fl4);
    float inv = 1.0f / den;
    float4 o;
    o.x = acc.x * inv + b4.x;
    o.y = acc.y * inv + b4.y;
    o.z = acc.z * inv + b4.z;
    o.w = acc.w * inv + b4.w;
    o.x = (o.x > 0.0f) ? o.x : expm1f(o.x);
    o.y = (o.y > 0.0f) ? o.y : expm1f(o.y);
    o.z = (o.z > 0.0f) ? o.z : expm1f(o.z);
    o.w = (o.w > 0.0f) ? o.w : expm1f(o.w);
    *(float4*)(hout + (size_t)node * 64 + fl4) = o;
}

// ---------------------------------------------------------------------------
// Global max pool: run-length (batch is sorted) + encoded atomicMax
// ---------------------------------------------------------------------------
__device__ __forceinline__ unsigned enc_f32(float f) {
    unsigned b = __float_as_uint(f);
    return (b & 0x80000000u) ? ~b : (b | 0x80000000u);
}

__global__ __launch_bounds__(256) void pool_kernel(const float* __restrict__ h,
                                                   const int* __restrict__ batch,
                                                   unsigned* __restrict__ genc, int n) {
    int lane = threadIdx.x & 63;
    int w = blockIdx.x * 4 + (threadIdx.x >> 6);
    int start = w * 64;
    if (start >= n) return;
    int end = start + 64; if (end > n) end = n;
    int cur = batch[start];
    float rm = -1e38f;
    for (int node = start; node < end; ++node) {
        int b = batch[node];                     // wave-uniform
        if (b != cur) {
            atomicMax(&genc[cur * 64 + lane], enc_f32(rm));
            cur = b;
            rm = -1e38f;
        }
        rm = fmaxf(rm, h[(size_t)node * 64 + lane]);
    }
    atomicMax(&genc[cur * 64 + lane], enc_f32(rm));
}

__global__ __launch_bounds__(64) void final_kernel(const unsigned* __restrict__ genc,
                                                   const float* __restrict__ linW,
                                                   const float* __restrict__ linb,
                                                   float* __restrict__ out) {
    int g = blockIdx.x;
    int lane = threadIdx.x;
    unsigned u = genc[g * 64 + lane];
    float v;
    if (u == 0u) {
        v = 0.0f;
    } else {
        unsigned b = (u & 0x80000000u) ? (u ^ 0x80000000u) : ~u;
        v = __uint_as_float(b);
    }
    float c0 = v * linW[lane * 2 + 0];
    float c1 = v * linW[lane * 2 + 1];
#pragma unroll
    for (int d = 32; d >= 1; d >>= 1) {
        c0 += __shfl_xor(c0, d, 64);
        c1 += __shfl_xor(c1, d, 64);
    }
    if (lane == 0) {
        out[g * 2 + 0] = c0 + linb[0];
        out[g * 2 + 1] = c1 + linb[1];
    }
}

// ---------------------------------------------------------------------------
// Launch
// ---------------------------------------------------------------------------
static inline size_t align_up(size_t v, size_t a) { return (v + a - 1) & ~(a - 1); }

extern "C" void kernel_launch(void* const* d_in, const int* in_sizes, int n_in,
                              void* d_out, int out_size, void* d_ws, size_t ws_size,
                              hipStream_t stream) {
    const float* x          = (const float*)d_in[0];
    const int*   edge_index = (const int*)d_in[1];
    const int*   batch      = (const int*)d_in[2];
    const float* W[5];
    const float* a_s[5];
    const float* a_d[5];
    const float* bias[5];
    for (int l = 0; l < 5; ++l) {
        W[l]    = (const float*)d_in[3 + 4 * l + 0];
        a_s[l]  = (const float*)d_in[3 + 4 * l + 1];
        a_d[l]  = (const float*)d_in[3 + 4 * l + 2];
        bias[l] = (const float*)d_in[3 + 4 * l + 3];
    }
    const float* linW = (const float*)d_in[23];
    const float* linb = (const float*)d_in[24];
    float* out = (float*)d_out;

    const int N = N_NODES;
    const int E = in_sizes[1] / 2;
    const int* srcp = edge_index;
    const int* dstp = edge_index + E;

    // workspace partition
    char* p = (char*)d_ws;
    int* bcount = (int*)p;        p += align_up((size_t)NBKT * 4, 256);
    int* bbase  = (int*)p;        p += align_up((size_t)(NBKT + 1) * 4, 256);
    int* bfill  = (int*)p;        p += align_up((size_t)NBKT * 4, 256);
    int* off    = (int*)p;        p += align_up((size_t)(N + 1) * 4, 256);
    int* esrc   = (int*)p;        p += align_up((size_t)E * 4, 256);
    float* lsA  = (float*)p;      p += align_up((size_t)N * 4, 256);
    float* ldA  = (float*)p;      p += align_up((size_t)N * 4, 256);
    float* lsB  = (float*)p;      p += align_up((size_t)N * 4, 256);
    float* ldB  = (float*)p;      p += align_up((size_t)N * 4, 256);
    __half* h16A = (__half*)p;    p += align_up((size_t)N * 64 * 2, 256);
    __half* h16B = (__half*)p;    p += align_up((size_t)N * 64 * 2, 256);
    float* h_a  = (float*)p;      p += align_up((size_t)N * 64 * 4, 256);
    unsigned* genc = (unsigned*)p; p += align_up((size_t)G_GRAPHS * 64 * 4, 256);

    // ebuck (E ints, 6.4MB, packed) aliases h_a (25.6MB): fully consumed by
    // bucket_csr before the final-layer gat writes h_a.
    int* ebuck = (int*)h_a;

    hipMemsetAsync(bcount, 0, (size_t)NBKT * 4, stream);
    hipMemsetAsync(genc, 0, (size_t)G_GRAPHS * 64 * 4, stream);

    int pb2 = (E + CHUNK_E - 1) / CHUNK_E;
    bucket_hist_kernel<<<pb2, 256, 0, stream>>>(dstp, bcount, E);
    bucket_scan_kernel<<<1, 256, 0, stream>>>(bcount, bbase, bfill, off, N);
    partition_kernel<<<pb2, 256, 0, stream>>>(srcp, dstp, bfill, ebuck, E);
    bucket_csr_kernel<<<NBKT, 256, 0, stream>>>(ebuck, bbase, off, esrc, N);

    int nb = (N + 15) / 16;   // 16 nodes per block
    int gt = (N + 127) / 128; // layer-0 GEMM: 128-node tiles

    // layer-0 GEMM -> set A
    gemm_tile_kernel<14, 16, 20><<<gt, 256, 0, stream>>>(
        x, W[0], a_s[0], a_d[0], h16A, lsA, ldA, N);
    // fused gat(l) + gemm(l+1), alternating buffers A->B->A->B->A
    gat_gemm_kernel<<<nb, 256, 0, stream>>>(
        h16A, lsA, ldA, off, esrc, bias[0], W[1], a_s[1], a_d[1],
        h16B, lsB, ldB, N);
    gat_gemm_kernel<<<nb, 256, 0, stream>>>(
        h16B, lsB, ldB, off, esrc, bias[1], W[2], a_s[2], a_d[2],
        h16A, lsA, ldA, N);
    gat_gemm_kernel<<<nb, 256, 0, stream>>>(
        h16A, lsA, ldA, off, esrc, bias[2], W[3], a_s[3], a_d[3],
        h16B, lsB, ldB, N);
    gat_gemm_kernel<<<nb, 256, 0, stream>>>(
        h16B, lsB, ldB, off, esrc, bias[3], W[4], a_s[4], a_d[4],
        h16A, lsA, ldA, N);
    // final layer: pure gat, fp32 out
    gat_final_kernel<<<nb, 256, 0, stream>>>(
        h16A, lsA, ldA, off, esrc, bias[4], h_a, N);

    int pw = (N + 63) / 64;
    int pbk = (pw + 3) / 4;
    pool_kernel<<<pbk, 256, 0, stream>>>(h_a, batch, genc, N);
    final_kernel<<<G_GRAPHS, 64, 0, stream>>>(genc, linW, linb, out);
}

// Round 14
// 445.220 us; speedup vs baseline: 1.1276x; 1.1276x over previous
//
#include <hip/hip_runtime.h>
#include <hip/hip_fp16.h>
#include <math.h>

#define N_NODES 100000
#define H_DIM 64
#define G_GRAPHS 512
#define NEG_SLOPE 0.2f

// bucketed CSR-build params
#define BSHIFT 9                         // 512 nodes per bucket
#define NBKT ((N_NODES + (1 << BSHIFT) - 1) >> BSHIFT)   // 196
#define CHUNK_E 4096                     // edges per partition block (16/thread)

#define DEG_CAP 64                       // staged edges per node (Poisson(16); deg>64 ~never, exact overflow path)

// packed edge: src in bits [0,17), in-bucket dst in bits [17,26)
#define PK_SRC(v)  ((v) & 0x1FFFF)
#define PK_LD(v)   ((v) >> 17)

// ---------------------------------------------------------------------------
// CSR build, bucket-first: no per-edge global atomics anywhere.
// ---------------------------------------------------------------------------

__global__ __launch_bounds__(256) void bucket_hist_kernel(const int* __restrict__ dst,
                                                          int* __restrict__ bcount, int E) {
    __shared__ int lh[NBKT];
    int t = threadIdx.x;
    for (int i = t; i < NBKT; i += 256) lh[i] = 0;
    __syncthreads();
    int base = blockIdx.x * CHUNK_E;
#pragma unroll
    for (int k = 0; k < 16; ++k) {
        int e = base + k * 256 + t;
        if (e < E) atomicAdd(&lh[dst[e] >> BSHIFT], 1);
    }
    __syncthreads();
    for (int i = t; i < NBKT; i += 256) {
        int c = lh[i];
        if (c) atomicAdd(&bcount[i], c);
    }
}

__global__ __launch_bounds__(256) void bucket_scan_kernel(const int* __restrict__ bcount,
                                                          int* __restrict__ bbase,
                                                          int* __restrict__ bfill,
                                                          int* __restrict__ off, int n) {
    __shared__ int sm[256];
    int t = threadIdx.x;
    sm[t] = (t < NBKT) ? bcount[t] : 0;
    __syncthreads();
    for (int d = 1; d < 256; d <<= 1) {
        int v = (t >= d) ? sm[t - d] : 0;
        __syncthreads();
        sm[t] += v;
        __syncthreads();
    }
    if (t < NBKT) {
        int ex = (t == 0) ? 0 : sm[t - 1];
        bbase[t] = ex;
        bfill[t] = ex;
    }
    if (t == 0) {
        bbase[NBKT] = sm[255];       // = E
        off[n] = sm[255];
    }
}

__global__ __launch_bounds__(256) void partition_kernel(const int* __restrict__ src,
                                                        const int* __restrict__ dst,
                                                        int* __restrict__ bfill,
                                                        int* __restrict__ ebuck, int E) {
    __shared__ int lh[NBKT];
    __shared__ int lbase[NBKT];
    int t = threadIdx.x;
    int base = blockIdx.x * CHUNK_E;
    for (int i = t; i < NBKT; i += 256) lh[i] = 0;
    __syncthreads();

    int pk[16], bk[16];
#pragma unroll
    for (int k = 0; k < 16; ++k) {
        int e = base + k * 256 + t;
        if (e < E) {
            int s = src[e];
            int d = dst[e];
            bk[k] = d >> BSHIFT;
            pk[k] = s | ((d & ((1 << BSHIFT) - 1)) << 17);
            atomicAdd(&lh[bk[k]], 1);
        } else {
            bk[k] = -1;
        }
    }
    __syncthreads();
    for (int i = t; i < NBKT; i += 256) {
        int c = lh[i];
        lbase[i] = c ? atomicAdd(&bfill[i], c) : 0;
        lh[i] = 0;
    }
    __syncthreads();
#pragma unroll
    for (int k = 0; k < 16; ++k) {
        if (bk[k] >= 0) {
            int r = atomicAdd(&lh[bk[k]], 1);
            ebuck[lbase[bk[k]] + r] = pk[k];
        }
    }
}

__global__ __launch_bounds__(256) void bucket_csr_kernel(const int* __restrict__ ebuck,
                                                         const int* __restrict__ bbase,
                                                         int* __restrict__ off,
                                                         int* __restrict__ esrc, int n) {
    __shared__ int cnt[512];
    __shared__ int loff[512];
    __shared__ int sm[256];
    int b = blockIdx.x;
    int t = threadIdx.x;
    int ebeg = bbase[b];
    int eend = bbase[b + 1];
    int nbeg = b << BSHIFT;
    int nloc = n - nbeg; if (nloc > 512) nloc = 512;

    cnt[t] = 0; cnt[t + 256] = 0;
    __syncthreads();
    for (int e = ebeg + t; e < eend; e += 256) {
        atomicAdd(&cnt[PK_LD(ebuck[e])], 1);
    }
    __syncthreads();
    int c0 = cnt[2 * t], c1 = cnt[2 * t + 1];
    sm[t] = c0 + c1;
    __syncthreads();
    for (int d = 1; d < 256; d <<= 1) {
        int v = (t >= d) ? sm[t - d] : 0;
        __syncthreads();
        sm[t] += v;
        __syncthreads();
    }
    int basep = (t == 0) ? 0 : sm[t - 1];
    loff[2 * t] = basep;
    loff[2 * t + 1] = basep + c0;
    cnt[2 * t] = 0; cnt[2 * t + 1] = 0;
    __syncthreads();
    for (int i = t; i < nloc; i += 256) off[nbeg + i] = ebeg + loff[i];
    for (int e = ebeg + t; e < eend; e += 256) {
        int v = ebuck[e];
        int d = PK_LD(v);
        int r = atomicAdd(&cnt[d], 1);
        esrc[ebeg + loff[d] + r] = PK_SRC(v);
    }
}

// ---------------------------------------------------------------------------
// Layer-0 GEMM + logits (round-4/5 structure, fp32 x input, fp16 h output).
// ---------------------------------------------------------------------------
template <int FIN, int FINP, int XSTR>
__global__ __launch_bounds__(256) void gemm_tile_kernel(
        const float* __restrict__ act, const float* __restrict__ W,
        const float* __restrict__ a_s, const float* __restrict__ a_d,
        __half* __restrict__ h16g,
        float* __restrict__ ls, float* __restrict__ ld,
        int n) {
    __shared__ float sx[128 * XSTR];
    __shared__ float sw[FINP * 64];
    int t = threadIdx.x;
    int tb = blockIdx.x * 128;
    int nrow = n - tb; if (nrow > 128) nrow = 128;

    {
        const float4* Wv = (const float4*)W;
        float4* swv = (float4*)sw;
        for (int i = t; i < FINP * 16; i += 256) {
            int k = i >> 4;
            swv[i] = (k < FIN) ? Wv[i] : make_float4(0.0f, 0.0f, 0.0f, 0.0f);
        }
    }
    {
        // scalar staging for unaligned FIN-float rows; pad cols [FIN,FINP) to 0
        int c = t & 15;
        for (int r = t >> 4; r < 128; r += 16) {
            float v = 0.0f;
            if (r < nrow && c < FIN) v = act[(size_t)(tb + r) * FIN + c];
            sx[r * XSTR + c] = v;
        }
    }
    __syncthreads();

    int f4 = t & 15;
    int ng = t >> 4;          // [0, 16)

    float4 acc[8];
#pragma unroll
    for (int i = 0; i < 8; ++i) acc[i] = make_float4(0.0f, 0.0f, 0.0f, 0.0f);

    for (int k4 = 0; k4 < FINP; k4 += 4) {
        float4 w0 = *(const float4*)(sw + (k4 + 0) * 64 + f4 * 4);
        float4 w1 = *(const float4*)(sw + (k4 + 1) * 64 + f4 * 4);
        float4 w2 = *(const float4*)(sw + (k4 + 2) * 64 + f4 * 4);
        float4 w3 = *(const float4*)(sw + (k4 + 3) * 64 + f4 * 4);
#pragma unroll
        for (int i = 0; i < 8; ++i) {
            float4 xv = *(const float4*)(sx + (ng + 16 * i) * XSTR + k4);
            acc[i].x = fmaf(xv.x, w0.x, acc[i].x);
            acc[i].y = fmaf(xv.x, w0.y, acc[i].y);
            acc[i].z = fmaf(xv.x, w0.z, acc[i].z);
            acc[i].w = fmaf(xv.x, w0.w, acc[i].w);
            acc[i].x = fmaf(xv.y, w1.x, acc[i].x);
            acc[i].y = fmaf(xv.y, w1.y, acc[i].y);
            acc[i].z = fmaf(xv.y, w1.z, acc[i].z);
            acc[i].w = fmaf(xv.y, w1.w, acc[i].w);
            acc[i].x = fmaf(xv.z, w2.x, acc[i].x);
            acc[i].y = fmaf(xv.z, w2.y, acc[i].y);
            acc[i].z = fmaf(xv.z, w2.z, acc[i].z);
            acc[i].w = fmaf(xv.z, w2.w, acc[i].w);
            acc[i].x = fmaf(xv.w, w3.x, acc[i].x);
            acc[i].y = fmaf(xv.w, w3.y, acc[i].y);
            acc[i].z = fmaf(xv.w, w3.z, acc[i].z);
            acc[i].w = fmaf(xv.w, w3.w, acc[i].w);
        }
    }

    float4 as4 = *(const float4*)(a_s + f4 * 4);
    float4 ad4 = *(const float4*)(a_d + f4 * 4);
#pragma unroll
    for (int i = 0; i < 8; ++i) {
        int r = ng + 16 * i;
        if (r < nrow) {
            int node = tb + r;
            __half2 plo = __floats2half2_rn(acc[i].x, acc[i].y);
            __half2 phi = __floats2half2_rn(acc[i].z, acc[i].w);
            uint2 pk;
            pk.x = *reinterpret_cast<unsigned*>(&plo);
            pk.y = *reinterpret_cast<unsigned*>(&phi);
            *reinterpret_cast<uint2*>(h16g + (size_t)node * 64 + f4 * 4) = pk;
            float vs = acc[i].x * as4.x + acc[i].y * as4.y +
                       acc[i].z * as4.z + acc[i].w * as4.w;
            float vd = acc[i].x * ad4.x + acc[i].y * ad4.y +
                       acc[i].z * ad4.z + acc[i].w * ad4.w;
            vs += __shfl_xor(vs, 1, 64); vd += __shfl_xor(vd, 1, 64);
            vs += __shfl_xor(vs, 2, 64); vd += __shfl_xor(vd, 2, 64);
            vs += __shfl_xor(vs, 4, 64); vd += __shfl_xor(vd, 4, 64);
            vs += __shfl_xor(vs, 8, 64); vd += __shfl_xor(vd, 8, 64);
            if (f4 == 0) { ls[node] = vs; ld[node] = vd; }
        }
    }
}

// ---------------------------------------------------------------------------
// FUSED: gat(layer l) + gemm(layer l+1) + logits(layer l+1).
// v14: DEG_CAP=64 (LDS 24KB -> 6 blocks/CU) and o-broadcast via the group's
// dead sq region (1 LDS write + 16 broadcast reads) instead of 64 bpermutes.
// ---------------------------------------------------------------------------
__global__ __launch_bounds__(256) void gat_gemm_kernel(
        const __half* __restrict__ h16_in, const float* __restrict__ ls_in,
        const float* __restrict__ ld_in, const int* __restrict__ off,
        const int* __restrict__ esrc, const float* __restrict__ bias,
        const float* __restrict__ Wn, const float* __restrict__ asn,
        const float* __restrict__ adn,
        __half* __restrict__ h16_out, float* __restrict__ ls_out,
        float* __restrict__ ld_out, int n) {
    __shared__ float sw[64 * 64];            // 16 KB: W(l+1)
    __shared__ int2 smq[16 * DEG_CAP];       // 8 KB: (src, ls->p) per group
    int t = threadIdx.x;
    // stage W with ALL threads (before any early return)
    {
        const float4* Wv = (const float4*)Wn;
        float4* swv = (float4*)sw;
        for (int i = t; i < 64 * 16; i += 256) swv[i] = Wv[i];
    }
    __syncthreads();   // no barriers after this point (intra-group ops only)

    int fl = t & 15;
    int g = t >> 4;
    int node = blockIdx.x * 16 + g;
    if (node >= n) return;
    int2* sq = smq + g * DEG_CAP;
    int fl4 = fl * 4;

    int jb = off[node];
    int je = off[node + 1];
    int deg = je - jb;
    int degc = (deg < DEG_CAP) ? deg : DEG_CAP;
    float ldv = ld_in[node];
    float lself = ls_in[node];

    // pass 1: gather ls, stage, running max (leaky is monotone)
    float mm = lself;
    for (int c = fl; c < degc; c += 16) {
        int s = esrc[jb + c];
        float v = ls_in[s];
        sq[c] = make_int2(s, __float_as_int(v));
        mm = fmaxf(mm, v);
    }
    for (int c = degc + fl; c < deg; c += 16) {
        mm = fmaxf(mm, ls_in[esrc[jb + c]]);
    }
    mm = fmaxf(mm, __shfl_xor(mm, 8, 64));
    mm = fmaxf(mm, __shfl_xor(mm, 4, 64));
    mm = fmaxf(mm, __shfl_xor(mm, 2, 64));
    mm = fmaxf(mm, __shfl_xor(mm, 1, 64));
    float mraw = mm + ldv;
    float m = (mraw >= 0.0f) ? mraw : NEG_SLOPE * mraw;

    // pass 2: ls -> p in LDS, lane-partial den
    float denl = 0.0f;
    for (int c = fl; c < degc; c += 16) {
        float e = __int_as_float(sq[c].y) + ldv;
        e = (e >= 0.0f) ? e : NEG_SLOPE * e;
        float p = __expf(e - m);
        sq[c].y = __float_as_int(p);
        denl += p;
    }
    int degc4 = (degc + 3) & ~3;
    if (fl < degc4 - degc) sq[degc + fl] = make_int2(node, 0);

    denl += __shfl_xor(denl, 8, 64);
    denl += __shfl_xor(denl, 4, 64);
    denl += __shfl_xor(denl, 2, 64);
    denl += __shfl_xor(denl, 1, 64);

    // self row early
    uint2 qs = *reinterpret_cast<const uint2*>(h16_in + (size_t)node * 64 + fl4);
    float2 sa = __half22float2(*reinterpret_cast<__half2*>(&qs.x));
    float2 sb = __half22float2(*reinterpret_cast<__half2*>(&qs.y));

    // gather loop: 4 independent 128B fp16 row loads in flight per group
    float4 acc = make_float4(0.0f, 0.0f, 0.0f, 0.0f);
    for (int c = 0; c < degc4; c += 4) {
        int2 e0 = sq[c + 0];
        int2 e1 = sq[c + 1];
        int2 e2 = sq[c + 2];
        int2 e3 = sq[c + 3];
        uint2 q0 = *reinterpret_cast<const uint2*>(h16_in + (size_t)e0.x * 64 + fl4);
        uint2 q1 = *reinterpret_cast<const uint2*>(h16_in + (size_t)e1.x * 64 + fl4);
        uint2 q2 = *reinterpret_cast<const uint2*>(h16_in + (size_t)e2.x * 64 + fl4);
        uint2 q3 = *reinterpret_cast<const uint2*>(h16_in + (size_t)e3.x * 64 + fl4);
        float p0 = __int_as_float(e0.y), p1 = __int_as_float(e1.y);
        float p2 = __int_as_float(e2.y), p3 = __int_as_float(e3.y);
        float2 a0 = __half22float2(*reinterpret_cast<__half2*>(&q0.x));
        float2 b0 = __half22float2(*reinterpret_cast<__half2*>(&q0.y));
        float2 a1 = __half22float2(*reinterpret_cast<__half2*>(&q1.x));
        float2 b1 = __half22float2(*reinterpret_cast<__half2*>(&q1.y));
        float2 a2 = __half22float2(*reinterpret_cast<__half2*>(&q2.x));
        float2 b2 = __half22float2(*reinterpret_cast<__half2*>(&q2.y));
        float2 a3 = __half22float2(*reinterpret_cast<__half2*>(&q3.x));
        float2 b3 = __half22float2(*reinterpret_cast<__half2*>(&q3.y));
        acc.x = fmaf(p0, a0.x, acc.x); acc.y = fmaf(p0, a0.y, acc.y);
        acc.z = fmaf(p0, b0.x, acc.z); acc.w = fmaf(p0, b0.y, acc.w);
        acc.x = fmaf(p1, a1.x, acc.x); acc.y = fmaf(p1, a1.y, acc.y);
        acc.z = fmaf(p1, b1.x, acc.z); acc.w = fmaf(p1, b1.y, acc.w);
        acc.x = fmaf(p2, a2.x, acc.x); acc.y = fmaf(p2, a2.y, acc.y);
        acc.z = fmaf(p2, b2.x, acc.z); acc.w = fmaf(p2, b2.y, acc.w);
        acc.x = fmaf(p3, a3.x, acc.x); acc.y = fmaf(p3, a3.y, acc.y);
        acc.z = fmaf(p3, b3.x, acc.z); acc.w = fmaf(p3, b3.y, acc.w);
    }

    // overflow tail (deg > DEG_CAP, ~never): exact, reads global directly
    float den_of = 0.0f;
    for (int j = jb + DEG_CAP; j < je; ++j) {
        int s = esrc[j];
        float e = ls_in[s] + ldv;
        e = (e >= 0.0f) ? e : NEG_SLOPE * e;
        float p = __expf(e - m);
        den_of += p;
        uint2 qv = *reinterpret_cast<const uint2*>(h16_in + (size_t)s * 64 + fl4);
        float2 va = __half22float2(*reinterpret_cast<__half2*>(&qv.x));
        float2 vb = __half22float2(*reinterpret_cast<__half2*>(&qv.y));
        acc.x = fmaf(p, va.x, acc.x);
        acc.y = fmaf(p, va.y, acc.y);
        acc.z = fmaf(p, vb.x, acc.z);
        acc.w = fmaf(p, vb.y, acc.w);
    }

    // self loop
    float e0s = lself + ldv;
    e0s = (e0s >= 0.0f) ? e0s : NEG_SLOPE * e0s;
    float p0s = __expf(e0s - m);
    float den = denl + den_of + p0s;
    acc.x = fmaf(p0s, sa.x, acc.x);
    acc.y = fmaf(p0s, sa.y, acc.y);
    acc.z = fmaf(p0s, sb.x, acc.z);
    acc.w = fmaf(p0s, sb.y, acc.w);

    const float4 b4 = *(const float4*)(bias + fl4);
    float inv = 1.0f / den;
    float4 o;
    o.x = acc.x * inv + b4.x;
    o.y = acc.y * inv + b4.y;
    o.z = acc.z * inv + b4.z;
    o.w = acc.w * inv + b4.w;
    o.x = (o.x > 0.0f) ? o.x : expm1f(o.x);
    o.y = (o.y > 0.0f) ? o.y : expm1f(o.y);
    o.z = (o.z > 0.0f) ? o.z : expm1f(o.z);
    o.w = (o.w > 0.0f) ? o.w : expm1f(o.w);

    // --- fused next-layer GEMM row: hn[f] = sum_k o[k] * Wn[k][f] ---
    // broadcast o via the group's dead sq region: 1 write + 16 broadcast reads
    // (same-wave LDS, no barrier needed; each group touches only its region)
    float4* so = (float4*)sq;
    so[fl] = o;
    float4 ha = make_float4(0.0f, 0.0f, 0.0f, 0.0f);
#pragma unroll
    for (int kk = 0; kk < 16; ++kk) {
        float4 ov = so[kk];                         // group-broadcast read
        const float4 w0 = *(const float4*)(sw + (4 * kk + 0) * 64 + fl4);
        const float4 w1 = *(const float4*)(sw + (4 * kk + 1) * 64 + fl4);
        const float4 w2 = *(const float4*)(sw + (4 * kk + 2) * 64 + fl4);
        const float4 w3 = *(const float4*)(sw + (4 * kk + 3) * 64 + fl4);
        ha.x = fmaf(ov.x, w0.x, ha.x); ha.y = fmaf(ov.x, w0.y, ha.y);
        ha.z = fmaf(ov.x, w0.z, ha.z); ha.w = fmaf(ov.x, w0.w, ha.w);
        ha.x = fmaf(ov.y, w1.x, ha.x); ha.y = fmaf(ov.y, w1.y, ha.y);
        ha.z = fmaf(ov.y, w1.z, ha.z); ha.w = fmaf(ov.y, w1.w, ha.w);
        ha.x = fmaf(ov.z, w2.x, ha.x); ha.y = fmaf(ov.z, w2.y, ha.y);
        ha.z = fmaf(ov.z, w2.z, ha.z); ha.w = fmaf(ov.z, w2.w, ha.w);
        ha.x = fmaf(ov.w, w3.x, ha.x); ha.y = fmaf(ov.w, w3.y, ha.y);
        ha.z = fmaf(ov.w, w3.z, ha.z); ha.w = fmaf(ov.w, w3.w, ha.w);
    }

    // store fp16 h row for next layer
    {
        __half2 plo = __floats2half2_rn(ha.x, ha.y);
        __half2 phi = __floats2half2_rn(ha.z, ha.w);
        uint2 pk;
        pk.x = *reinterpret_cast<unsigned*>(&plo);
        pk.y = *reinterpret_cast<unsigned*>(&phi);
        *reinterpret_cast<uint2*>(h16_out + (size_t)node * 64 + fl4) = pk;
    }
    // next-layer logits
    float4 as4 = *(const float4*)(asn + fl4);
    float4 ad4 = *(const float4*)(adn + fl4);
    float vs = ha.x * as4.x + ha.y * as4.y + ha.z * as4.z + ha.w * as4.w;
    float vd = ha.x * ad4.x + ha.y * ad4.y + ha.z * ad4.z + ha.w * ad4.w;
    vs += __shfl_xor(vs, 1, 64); vd += __shfl_xor(vd, 1, 64);
    vs += __shfl_xor(vs, 2, 64); vd += __shfl_xor(vd, 2, 64);
    vs += __shfl_xor(vs, 4, 64); vd += __shfl_xor(vd, 4, 64);
    vs += __shfl_xor(vs, 8, 64); vd += __shfl_xor(vd, 8, 64);
    if (fl == 0) { ls_out[node] = vs; ld_out[node] = vd; }
}

// ---------------------------------------------------------------------------
// Final-layer GAT (no fused gemm): fp16 gather, fp32 activation output.
// ---------------------------------------------------------------------------
__global__ __launch_bounds__(256) void gat_final_kernel(
        const __half* __restrict__ h16_in,
        const float* __restrict__ ls_in,
        const float* __restrict__ ld_in, const int* __restrict__ off,
        const int* __restrict__ esrc, const float* __restrict__ bias,
        float* __restrict__ hout, int n) {
    __shared__ int2 smq[16 * DEG_CAP];
    int t = threadIdx.x;
    int fl = t & 15;
    int g = t >> 4;
    int node = blockIdx.x * 16 + g;
    if (node >= n) return;
    int2* sq = smq + g * DEG_CAP;
    int fl4 = fl * 4;

    int jb = off[node];
    int je = off[node + 1];
    int deg = je - jb;
    int degc = (deg < DEG_CAP) ? deg : DEG_CAP;
    float ldv = ld_in[node];
    float lself = ls_in[node];

    float mm = lself;
    for (int c = fl; c < degc; c += 16) {
        int s = esrc[jb + c];
        float v = ls_in[s];
        sq[c] = make_int2(s, __float_as_int(v));
        mm = fmaxf(mm, v);
    }
    for (int c = degc + fl; c < deg; c += 16) {
        mm = fmaxf(mm, ls_in[esrc[jb + c]]);
    }
    mm = fmaxf(mm, __shfl_xor(mm, 8, 64));
    mm = fmaxf(mm, __shfl_xor(mm, 4, 64));
    mm = fmaxf(mm, __shfl_xor(mm, 2, 64));
    mm = fmaxf(mm, __shfl_xor(mm, 1, 64));
    float mraw = mm + ldv;
    float m = (mraw >= 0.0f) ? mraw : NEG_SLOPE * mraw;

    float denl = 0.0f;
    for (int c = fl; c < degc; c += 16) {
        float e = __int_as_float(sq[c].y) + ldv;
        e = (e >= 0.0f) ? e : NEG_SLOPE * e;
        float p = __expf(e - m);
        sq[c].y = __float_as_int(p);
        denl += p;
    }
    int degc4 = (degc + 3) & ~3;
    if (fl < degc4 - degc) sq[degc + fl] = make_int2(node, 0);

    denl += __shfl_xor(denl, 8, 64);
    denl += __shfl_xor(denl, 4, 64);
    denl += __shfl_xor(denl, 2, 64);
    denl += __shfl_xor(denl, 1, 64);

    uint2 qs = *reinterpret_cast<const uint2*>(h16_in + (size_t)node * 64 + fl4);
    float2 sa = __half22float2(*reinterpret_cast<__half2*>(&qs.x));
    float2 sb = __half22float2(*reinterpret_cast<__half2*>(&qs.y));

    float4 acc = make_float4(0.0f, 0.0f, 0.0f, 0.0f);
    for (int c = 0; c < degc4; c += 4) {
        int2 e0 = sq[c + 0];
        int2 e1 = sq[c + 1];
        int2 e2 = sq[c + 2];
        int2 e3 = sq[c + 3];
        uint2 q0 = *reinterpret_cast<const uint2*>(h16_in + (size_t)e0.x * 64 + fl4);
        uint2 q1 = *reinterpret_cast<const uint2*>(h16_in + (size_t)e1.x * 64 + fl4);
        uint2 q2 = *reinterpret_cast<const uint2*>(h16_in + (size_t)e2.x * 64 + fl4);
        uint2 q3 = *reinterpret_cast<const uint2*>(h16_in + (size_t)e3.x * 64 + fl4);
        float p0 = __int_as_float(e0.y), p1 = __int_as_float(e1.y);
        float p2 = __int_as_float(e2.y), p3 = __int_as_float(e3.y);
        float2 a0 = __half22float2(*reinterpret_cast<__half2*>(&q0.x));
        float2 b0 = __half22float2(*reinterpret_cast<__half2*>(&q0.y));
        float2 a1 = __half22float2(*reinterpret_cast<__half2*>(&q1.x));
        float2 b1 = __half22float2(*reinterpret_cast<__half2*>(&q1.y));
        float2 a2 = __half22float2(*reinterpret_cast<__half2*>(&q2.x));
        float2 b2 = __half22float2(*reinterpret_cast<__half2*>(&q2.y));
        float2 a3 = __half22float2(*reinterpret_cast<__half2*>(&q3.x));
        float2 b3 = __half22float2(*reinterpret_cast<__half2*>(&q3.y));
        acc.x = fmaf(p0, a0.x, acc.x); acc.y = fmaf(p0, a0.y, acc.y);
        acc.z = fmaf(p0, b0.x, acc.z); acc.w = fmaf(p0, b0.y, acc.w);
        acc.x = fmaf(p1, a1.x, acc.x); acc.y = fmaf(p1, a1.y, acc.y);
        acc.z = fmaf(p1, b1.x, acc.z); acc.w = fmaf(p1, b1.y, acc.w);
        acc.x = fmaf(p2, a2.x, acc.x); acc.y = fmaf(p2, a2.y, acc.y);
        acc.z = fmaf(p2, b2.x, acc.z); acc.w = fmaf(p2, b2.y, acc.w);
        acc.x = fmaf(p3, a3.x, acc.x); acc.y = fmaf(p3, a3.y, acc.y);
        acc.z = fmaf(p3, b3.x, acc.z); acc.w = fmaf(p3, b3.y, acc.w);
    }

    float den_of = 0.0f;
    for (int j = jb + DEG_CAP; j < je; ++j) {
        int s = esrc[j];
        float e = ls_in[s] + ldv;
        e = (e >= 0.0f) ? e : NEG_SLOPE * e;
        float p = __expf(e - m);
        den_of += p;
        uint2 qv = *reinterpret_cast<const uint2*>(h16_in + (size_t)s * 64 + fl4);
        float2 va = __half22float2(*reinterpret_cast<__half2*>(&qv.x));
        float2 vb = __half22float2(*reinterpret_cast<__half2*>(&qv.y));
        acc.x = fmaf(p, va.x, acc.x);
        acc.y = fmaf(p, va.y, acc.y);
        acc.z = fmaf(p, vb.x, acc.z);
        acc.w = fmaf(p, vb.y, acc.w);
    }

    float e0s = lself + ldv;
    e0s = (e0s >= 0.0f) ? e0s : NEG_SLOPE * e0s;
    float p0s = __expf(e0s - m);
    float den = denl + den_of + p0s;
    acc.x = fmaf(p0s, sa.x, acc.x);
    acc.y = fmaf(p0s, sa.y, acc.y);
    acc.z = fmaf(p0s, sb.x, acc.z);
    acc.w = fmaf(p0s, sb.y, acc.w);

    const float4 b4 = *(const float4*)(bias + fl4);
    float inv = 1.0f / den;
    float4 o;
    o.x = acc.x * inv + b4.x;
    o.y = acc.y * inv + b4.y;
    o.z = acc.z * inv + b4.z;
    o.w = acc.w * inv + b4.w;
    o.x = (o.x > 0.0f) ? o.x : expm1f(o.x);
    o.y = (o.y > 0.0f) ? o.y : expm1f(o.y);
    o.z = (o.z > 0.0f) ? o.z : expm1f(o.z);
    o.w = (o.w > 0.0f) ? o.w : expm1f(o.w);
    *(float4*)(hout + (size_t)node * 64 + fl4) = o;
}

// ---------------------------------------------------------------------------
// Global max pool: run-length (batch is sorted) + encoded atomicMax
// ---------------------------------------------------------------------------
__device__ __forceinline__ unsigned enc_f32(float f) {
    unsigned b = __float_as_uint(f);
    return (b & 0x80000000u) ? ~b : (b | 0x80000000u);
}

__global__ __launch_bounds__(256) void pool_kernel(const float* __restrict__ h,
                                                   const int* __restrict__ batch,
                                                   unsigned* __restrict__ genc, int n) {
    int lane = threadIdx.x & 63;
    int w = blockIdx.x * 4 + (threadIdx.x >> 6);
    int start = w * 64;
    if (start >= n) return;
    int end = start + 64; if (end > n) end = n;
    int cur = batch[start];
    float rm = -1e38f;
    for (int node = start; node < end; ++node) {
        int b = batch[node];                     // wave-uniform
        if (b != cur) {
            atomicMax(&genc[cur * 64 + lane], enc_f32(rm));
            cur = b;
            rm = -1e38f;
        }
        rm = fmaxf(rm, h[(size_t)node * 64 + lane]);
    }
    atomicMax(&genc[cur * 64 + lane], enc_f32(rm));
}

__global__ __launch_bounds__(64) void final_kernel(const unsigned* __restrict__ genc,
                                                   const float* __restrict__ linW,
                                                   const float* __restrict__ linb,
                                                   float* __restrict__ out) {
    int g = blockIdx.x;
    int lane = threadIdx.x;
    unsigned u = genc[g * 64 + lane];
    float v;
    if (u == 0u) {
        v = 0.0f;
    } else {
        unsigned b = (u & 0x80000000u) ? (u ^ 0x80000000u) : ~u;
        v = __uint_as_float(b);
    }
    float c0 = v * linW[lane * 2 + 0];
    float c1 = v * linW[lane * 2 + 1];
#pragma unroll
    for (int d = 32; d >= 1; d >>= 1) {
        c0 += __shfl_xor(c0, d, 64);
        c1 += __shfl_xor(c1, d, 64);
    }
    if (lane == 0) {
        out[g * 2 + 0] = c0 + linb[0];
        out[g * 2 + 1] = c1 + linb[1];
    }
}

// ---------------------------------------------------------------------------
// Launch
// ---------------------------------------------------------------------------
static inline size_t align_up(size_t v, size_t a) { return (v + a - 1) & ~(a - 1); }

extern "C" void kernel_launch(void* const* d_in, const int* in_sizes, int n_in,
                              void* d_out, int out_size, void* d_ws, size_t ws_size,
                              hipStream_t stream) {
    const float* x          = (const float*)d_in[0];
    const int*   edge_index = (const int*)d_in[1];
    const int*   batch      = (const int*)d_in[2];
    const float* W[5];
    const float* a_s[5];
    const float* a_d[5];
    const float* bias[5];
    for (int l = 0; l < 5; ++l) {
        W[l]    = (const float*)d_in[3 + 4 * l + 0];
        a_s[l]  = (const float*)d_in[3 + 4 * l + 1];
        a_d[l]  = (const float*)d_in[3 + 4 * l + 2];
        bias[l] = (const float*)d_in[3 + 4 * l + 3];
    }
    const float* linW = (const float*)d_in[23];
    const float* linb = (const float*)d_in[24];
    float* out = (float*)d_out;

    const int N = N_NODES;
    const int E = in_sizes[1] / 2;
    const int* srcp = edge_index;
    const int* dstp = edge_index + E;

    // workspace partition
    char* p = (char*)d_ws;
    int* bcount = (int*)p;        p += align_up((size_t)NBKT * 4, 256);
    int* bbase  = (int*)p;        p += align_up((size_t)(NBKT + 1) * 4, 256);
    int* bfill  = (int*)p;        p += align_up((size_t)NBKT * 4, 256);
    int* off    = (int*)p;        p += align_up((size_t)(N + 1) * 4, 256);
    int* esrc   = (int*)p;        p += align_up((size_t)E * 4, 256);
    float* lsA  = (float*)p;      p += align_up((size_t)N * 4, 256);
    float* ldA  = (float*)p;      p += align_up((size_t)N * 4, 256);
    float* lsB  = (float*)p;      p += align_up((size_t)N * 4, 256);
    float* ldB  = (float*)p;      p += align_up((size_t)N * 4, 256);
    __half* h16A = (__half*)p;    p += align_up((size_t)N * 64 * 2, 256);
    __half* h16B = (__half*)p;    p += align_up((size_t)N * 64 * 2, 256);
    float* h_a  = (float*)p;      p += align_up((size_t)N * 64 * 4, 256);
    unsigned* genc = (unsigned*)p; p += align_up((size_t)G_GRAPHS * 64 * 4, 256);

    // ebuck (E ints, 6.4MB, packed) aliases h_a (25.6MB): fully consumed by
    // bucket_csr before the final-layer gat writes h_a.
    int* ebuck = (int*)h_a;

    hipMemsetAsync(bcount, 0, (size_t)NBKT * 4, stream);
    hipMemsetAsync(genc, 0, (size_t)G_GRAPHS * 64 * 4, stream);

    int pb2 = (E + CHUNK_E - 1) / CHUNK_E;
    bucket_hist_kernel<<<pb2, 256, 0, stream>>>(dstp, bcount, E);
    bucket_scan_kernel<<<1, 256, 0, stream>>>(bcount, bbase, bfill, off, N);
    partition_kernel<<<pb2, 256, 0, stream>>>(srcp, dstp, bfill, ebuck, E);
    bucket_csr_kernel<<<NBKT, 256, 0, stream>>>(ebuck, bbase, off, esrc, N);

    int nb = (N + 15) / 16;   // 16 nodes per block
    int gt = (N + 127) / 128; // layer-0 GEMM: 128-node tiles

    // layer-0 GEMM -> set A
    gemm_tile_kernel<14, 16, 20><<<gt, 256, 0, stream>>>(
        x, W[0], a_s[0], a_d[0], h16A, lsA, ldA, N);
    // fused gat(l) + gemm(l+1), alternating buffers A->B->A->B->A
    gat_gemm_kernel<<<nb, 256, 0, stream>>>(
        h16A, lsA, ldA, off, esrc, bias[0], W[1], a_s[1], a_d[1],
        h16B, lsB, ldB, N);
    gat_gemm_kernel<<<nb, 256, 0, stream>>>(
        h16B, lsB, ldB, off, esrc, bias[1], W[2], a_s[2], a_d[2],
        h16A, lsA, ldA, N);
    gat_gemm_kernel<<<nb, 256, 0, stream>>>(
        h16A, lsA, ldA, off, esrc, bias[2], W[3], a_s[3], a_d[3],
        h16B, lsB, ldB, N);
    gat_gemm_kernel<<<nb, 256, 0, stream>>>(
        h16B, lsB, ldB, off, esrc, bias[3], W[4], a_s[4], a_d[4],
        h16A, lsA, ldA, N);
    // final layer: pure gat, fp32 out
    gat_final_kernel<<<nb, 256, 0, stream>>>(
        h16A, lsA, ldA, off, esrc, bias[4], h_a, N);

    int pw = (N + 63) / 64;
    int pbk = (pw + 3) / 4;
    pool_kernel<<<pbk, 256, 0, stream>>>(h_a, batch, genc, N);
    final_kernel<<<G_GRAPHS, 64, 0, stream>>>(genc, linW, linb, out);
}

// Round 15
// 427.263 us; speedup vs baseline: 1.1750x; 1.0420x over previous
//
#include <hip/hip_runtime.h>
#include <hip/hip_fp16.h>
#include <math.h>

#define N_NODES 100000
#define H_DIM 64
#define G_GRAPHS 512
#define NEG_SLOPE 0.2f

// bucketed CSR-build params
#define BSHIFT 9                         // 512 nodes per bucket
#define NBKT ((N_NODES + (1 << BSHIFT) - 1) >> BSHIFT)   // 196
#define CHUNK_E 4096                     // edges per partition block (16/thread)

#define DEG_CAP 32                       // staged edges/node; P(Poisson(16)>32)~1e-4, exact overflow path

// packed edge: src in bits [0,17), in-bucket dst in bits [17,26)
#define PK_SRC(v)  ((v) & 0x1FFFF)
#define PK_LD(v)   ((v) >> 17)

// ---------------------------------------------------------------------------
// CSR build, bucket-first: no per-edge global atomics anywhere.
// ---------------------------------------------------------------------------

__global__ __launch_bounds__(256) void bucket_hist_kernel(const int* __restrict__ dst,
                                                          int* __restrict__ bcount, int E) {
    __shared__ int lh[NBKT];
    int t = threadIdx.x;
    for (int i = t; i < NBKT; i += 256) lh[i] = 0;
    __syncthreads();
    int base = blockIdx.x * CHUNK_E;
#pragma unroll
    for (int k = 0; k < 16; ++k) {
        int e = base + k * 256 + t;
        if (e < E) atomicAdd(&lh[dst[e] >> BSHIFT], 1);
    }
    __syncthreads();
    for (int i = t; i < NBKT; i += 256) {
        int c = lh[i];
        if (c) atomicAdd(&bcount[i], c);
    }
}

__global__ __launch_bounds__(256) void bucket_scan_kernel(const int* __restrict__ bcount,
                                                          int* __restrict__ bbase,
                                                          int* __restrict__ bfill,
                                                          int* __restrict__ off, int n) {
    __shared__ int sm[256];
    int t = threadIdx.x;
    sm[t] = (t < NBKT) ? bcount[t] : 0;
    __syncthreads();
    for (int d = 1; d < 256; d <<= 1) {
        int v = (t >= d) ? sm[t - d] : 0;
        __syncthreads();
        sm[t] += v;
        __syncthreads();
    }
    if (t < NBKT) {
        int ex = (t == 0) ? 0 : sm[t - 1];
        bbase[t] = ex;
        bfill[t] = ex;
    }
    if (t == 0) {
        bbase[NBKT] = sm[255];       // = E
        off[n] = sm[255];
    }
}

__global__ __launch_bounds__(256) void partition_kernel(const int* __restrict__ src,
                                                        const int* __restrict__ dst,
                                                        int* __restrict__ bfill,
                                                        int* __restrict__ ebuck, int E) {
    __shared__ int lh[NBKT];
    __shared__ int lbase[NBKT];
    int t = threadIdx.x;
    int base = blockIdx.x * CHUNK_E;
    for (int i = t; i < NBKT; i += 256) lh[i] = 0;
    __syncthreads();

    int pk[16], bk[16];
#pragma unroll
    for (int k = 0; k < 16; ++k) {
        int e = base + k * 256 + t;
        if (e < E) {
            int s = src[e];
            int d = dst[e];
            bk[k] = d >> BSHIFT;
            pk[k] = s | ((d & ((1 << BSHIFT) - 1)) << 17);
            atomicAdd(&lh[bk[k]], 1);
        } else {
            bk[k] = -1;
        }
    }
    __syncthreads();
    for (int i = t; i < NBKT; i += 256) {
        int c = lh[i];
        lbase[i] = c ? atomicAdd(&bfill[i], c) : 0;
        lh[i] = 0;
    }
    __syncthreads();
#pragma unroll
    for (int k = 0; k < 16; ++k) {
        if (bk[k] >= 0) {
            int r = atomicAdd(&lh[bk[k]], 1);
            ebuck[lbase[bk[k]] + r] = pk[k];
        }
    }
}

__global__ __launch_bounds__(256) void bucket_csr_kernel(const int* __restrict__ ebuck,
                                                         const int* __restrict__ bbase,
                                                         int* __restrict__ off,
                                                         int* __restrict__ esrc, int n) {
    __shared__ int cnt[512];
    __shared__ int loff[512];
    __shared__ int sm[256];
    int b = blockIdx.x;
    int t = threadIdx.x;
    int ebeg = bbase[b];
    int eend = bbase[b + 1];
    int nbeg = b << BSHIFT;
    int nloc = n - nbeg; if (nloc > 512) nloc = 512;

    cnt[t] = 0; cnt[t + 256] = 0;
    __syncthreads();
    for (int e = ebeg + t; e < eend; e += 256) {
        atomicAdd(&cnt[PK_LD(ebuck[e])], 1);
    }
    __syncthreads();
    int c0 = cnt[2 * t], c1 = cnt[2 * t + 1];
    sm[t] = c0 + c1;
    __syncthreads();
    for (int d = 1; d < 256; d <<= 1) {
        int v = (t >= d) ? sm[t - d] : 0;
        __syncthreads();
        sm[t] += v;
        __syncthreads();
    }
    int basep = (t == 0) ? 0 : sm[t - 1];
    loff[2 * t] = basep;
    loff[2 * t + 1] = basep + c0;
    cnt[2 * t] = 0; cnt[2 * t + 1] = 0;
    __syncthreads();
    for (int i = t; i < nloc; i += 256) off[nbeg + i] = ebeg + loff[i];
    for (int e = ebeg + t; e < eend; e += 256) {
        int v = ebuck[e];
        int d = PK_LD(v);
        int r = atomicAdd(&cnt[d], 1);
        esrc[ebeg + loff[d] + r] = PK_SRC(v);
    }
}

// ---------------------------------------------------------------------------
// Layer-0 GEMM + logits (round-4/5 structure, fp32 x input, fp16 h output).
// ---------------------------------------------------------------------------
template <int FIN, int FINP, int XSTR>
__global__ __launch_bounds__(256) void gemm_tile_kernel(
        const float* __restrict__ act, const float* __restrict__ W,
        const float* __restrict__ a_s, const float* __restrict__ a_d,
        __half* __restrict__ h16g,
        float* __restrict__ ls, float* __restrict__ ld,
        int n) {
    __shared__ float sx[128 * XSTR];
    __shared__ float sw[FINP * 64];
    int t = threadIdx.x;
    int tb = blockIdx.x * 128;
    int nrow = n - tb; if (nrow > 128) nrow = 128;

    {
        const float4* Wv = (const float4*)W;
        float4* swv = (float4*)sw;
        for (int i = t; i < FINP * 16; i += 256) {
            int k = i >> 4;
            swv[i] = (k < FIN) ? Wv[i] : make_float4(0.0f, 0.0f, 0.0f, 0.0f);
        }
    }
    {
        // scalar staging for unaligned FIN-float rows; pad cols [FIN,FINP) to 0
        int c = t & 15;
        for (int r = t >> 4; r < 128; r += 16) {
            float v = 0.0f;
            if (r < nrow && c < FIN) v = act[(size_t)(tb + r) * FIN + c];
            sx[r * XSTR + c] = v;
        }
    }
    __syncthreads();

    int f4 = t & 15;
    int ng = t >> 4;          // [0, 16)

    float4 acc[8];
#pragma unroll
    for (int i = 0; i < 8; ++i) acc[i] = make_float4(0.0f, 0.0f, 0.0f, 0.0f);

    for (int k4 = 0; k4 < FINP; k4 += 4) {
        float4 w0 = *(const float4*)(sw + (k4 + 0) * 64 + f4 * 4);
        float4 w1 = *(const float4*)(sw + (k4 + 1) * 64 + f4 * 4);
        float4 w2 = *(const float4*)(sw + (k4 + 2) * 64 + f4 * 4);
        float4 w3 = *(const float4*)(sw + (k4 + 3) * 64 + f4 * 4);
#pragma unroll
        for (int i = 0; i < 8; ++i) {
            float4 xv = *(const float4*)(sx + (ng + 16 * i) * XSTR + k4);
            acc[i].x = fmaf(xv.x, w0.x, acc[i].x);
            acc[i].y = fmaf(xv.x, w0.y, acc[i].y);
            acc[i].z = fmaf(xv.x, w0.z, acc[i].z);
            acc[i].w = fmaf(xv.x, w0.w, acc[i].w);
            acc[i].x = fmaf(xv.y, w1.x, acc[i].x);
            acc[i].y = fmaf(xv.y, w1.y, acc[i].y);
            acc[i].z = fmaf(xv.y, w1.z, acc[i].z);
            acc[i].w = fmaf(xv.y, w1.w, acc[i].w);
            acc[i].x = fmaf(xv.z, w2.x, acc[i].x);
            acc[i].y = fmaf(xv.z, w2.y, acc[i].y);
            acc[i].z = fmaf(xv.z, w2.z, acc[i].z);
            acc[i].w = fmaf(xv.z, w2.w, acc[i].w);
            acc[i].x = fmaf(xv.w, w3.x, acc[i].x);
            acc[i].y = fmaf(xv.w, w3.y, acc[i].y);
            acc[i].z = fmaf(xv.w, w3.z, acc[i].z);
            acc[i].w = fmaf(xv.w, w3.w, acc[i].w);
        }
    }

    float4 as4 = *(const float4*)(a_s + f4 * 4);
    float4 ad4 = *(const float4*)(a_d + f4 * 4);
#pragma unroll
    for (int i = 0; i < 8; ++i) {
        int r = ng + 16 * i;
        if (r < nrow) {
            int node = tb + r;
            __half2 plo = __floats2half2_rn(acc[i].x, acc[i].y);
            __half2 phi = __floats2half2_rn(acc[i].z, acc[i].w);
            uint2 pk;
            pk.x = *reinterpret_cast<unsigned*>(&plo);
            pk.y = *reinterpret_cast<unsigned*>(&phi);
            *reinterpret_cast<uint2*>(h16g + (size_t)node * 64 + f4 * 4) = pk;
            float vs = acc[i].x * as4.x + acc[i].y * as4.y +
                       acc[i].z * as4.z + acc[i].w * as4.w;
            float vd = acc[i].x * ad4.x + acc[i].y * ad4.y +
                       acc[i].z * ad4.z + acc[i].w * ad4.w;
            vs += __shfl_xor(vs, 1, 64); vd += __shfl_xor(vd, 1, 64);
            vs += __shfl_xor(vs, 2, 64); vd += __shfl_xor(vd, 2, 64);
            vs += __shfl_xor(vs, 4, 64); vd += __shfl_xor(vd, 4, 64);
            vs += __shfl_xor(vs, 8, 64); vd += __shfl_xor(vd, 8, 64);
            if (f4 == 0) { ls[node] = vs; ld[node] = vd; }
        }
    }
}

// ---------------------------------------------------------------------------
// FUSED: gat(layer l) + gemm(layer l+1) + logits(layer l+1).
// v15: DEG_CAP=32 -> LDS 20KB -> 8 blocks/CU (32 waves, HW max); per-group
// LDS index skew (c+4g)&31 / (kk+g)&15 puts the 4 groups' accesses on
// distinct banks (was a 4-way conflict: group regions are bank-aligned).
// ---------------------------------------------------------------------------
__global__ __launch_bounds__(256) void gat_gemm_kernel(
        const __half* __restrict__ h16_in, const float* __restrict__ ls_in,
        const float* __restrict__ ld_in, const int* __restrict__ off,
        const int* __restrict__ esrc, const float* __restrict__ bias,
        const float* __restrict__ Wn, const float* __restrict__ asn,
        const float* __restrict__ adn,
        __half* __restrict__ h16_out, float* __restrict__ ls_out,
        float* __restrict__ ld_out, int n) {
    __shared__ float sw[64 * 64];            // 16 KB: W(l+1)
    __shared__ int2 smq[16 * DEG_CAP];       // 4 KB: (src, ls->p) per group
    int t = threadIdx.x;
    // stage W with ALL threads (before any early return)
    {
        const float4* Wv = (const float4*)Wn;
        float4* swv = (float4*)sw;
        for (int i = t; i < 64 * 16; i += 256) swv[i] = Wv[i];
    }
    __syncthreads();   // no barriers after this point (intra-group ops only)

    int fl = t & 15;
    int g = t >> 4;
    int node = blockIdx.x * 16 + g;
    if (node >= n) return;
    int2* sq = smq + g * DEG_CAP;
    int fl4 = fl * 4;
    int sk4 = 4 * g;                          // per-group bank skew

    int jb = off[node];
    int je = off[node + 1];
    int deg = je - jb;
    int degc = (deg < DEG_CAP) ? deg : DEG_CAP;
    float ldv = ld_in[node];
    float lself = ls_in[node];

    // pass 1: gather ls, stage (skewed), running max (leaky is monotone)
    float mm = lself;
    for (int c = fl; c < degc; c += 16) {
        int s = esrc[jb + c];
        float v = ls_in[s];
        sq[(c + sk4) & (DEG_CAP - 1)] = make_int2(s, __float_as_int(v));
        mm = fmaxf(mm, v);
    }
    for (int c = degc + fl; c < deg; c += 16) {
        mm = fmaxf(mm, ls_in[esrc[jb + c]]);
    }
    mm = fmaxf(mm, __shfl_xor(mm, 8, 64));
    mm = fmaxf(mm, __shfl_xor(mm, 4, 64));
    mm = fmaxf(mm, __shfl_xor(mm, 2, 64));
    mm = fmaxf(mm, __shfl_xor(mm, 1, 64));
    float mraw = mm + ldv;
    float m = (mraw >= 0.0f) ? mraw : NEG_SLOPE * mraw;

    // pass 2: ls -> p in LDS, lane-partial den
    float denl = 0.0f;
    for (int c = fl; c < degc; c += 16) {
        int ci = (c + sk4) & (DEG_CAP - 1);
        float e = __int_as_float(sq[ci].y) + ldv;
        e = (e >= 0.0f) ? e : NEG_SLOPE * e;
        float p = __expf(e - m);
        sq[ci].y = __float_as_int(p);
        denl += p;
    }
    int degc4 = (degc + 3) & ~3;
    if (fl < degc4 - degc) sq[(degc + fl + sk4) & (DEG_CAP - 1)] = make_int2(node, 0);

    denl += __shfl_xor(denl, 8, 64);
    denl += __shfl_xor(denl, 4, 64);
    denl += __shfl_xor(denl, 2, 64);
    denl += __shfl_xor(denl, 1, 64);

    // self row early
    uint2 qs = *reinterpret_cast<const uint2*>(h16_in + (size_t)node * 64 + fl4);
    float2 sa = __half22float2(*reinterpret_cast<__half2*>(&qs.x));
    float2 sb = __half22float2(*reinterpret_cast<__half2*>(&qs.y));

    // gather loop: 4 independent 128B fp16 row loads in flight per group
    float4 acc = make_float4(0.0f, 0.0f, 0.0f, 0.0f);
    for (int c = 0; c < degc4; c += 4) {
        int2 e0 = sq[(c + 0 + sk4) & (DEG_CAP - 1)];
        int2 e1 = sq[(c + 1 + sk4) & (DEG_CAP - 1)];
        int2 e2 = sq[(c + 2 + sk4) & (DEG_CAP - 1)];
        int2 e3 = sq[(c + 3 + sk4) & (DEG_CAP - 1)];
        uint2 q0 = *reinterpret_cast<const uint2*>(h16_in + (size_t)e0.x * 64 + fl4);
        uint2 q1 = *reinterpret_cast<const uint2*>(h16_in + (size_t)e1.x * 64 + fl4);
        uint2 q2 = *reinterpret_cast<const uint2*>(h16_in + (size_t)e2.x * 64 + fl4);
        uint2 q3 = *reinterpret_cast<const uint2*>(h16_in + (size_t)e3.x * 64 + fl4);
        float p0 = __int_as_float(e0.y), p1 = __int_as_float(e1.y);
        float p2 = __int_as_float(e2.y), p3 = __int_as_float(e3.y);
        float2 a0 = __half22float2(*reinterpret_cast<__half2*>(&q0.x));
        float2 b0 = __half22float2(*reinterpret_cast<__half2*>(&q0.y));
        float2 a1 = __half22float2(*reinterpret_cast<__half2*>(&q1.x));
        float2 b1 = __half22float2(*reinterpret_cast<__half2*>(&q1.y));
        float2 a2 = __half22float2(*reinterpret_cast<__half2*>(&q2.x));
        float2 b2 = __half22float2(*reinterpret_cast<__half2*>(&q2.y));
        float2 a3 = __half22float2(*reinterpret_cast<__half2*>(&q3.x));
        float2 b3 = __half22float2(*reinterpret_cast<__half2*>(&q3.y));
        acc.x = fmaf(p0, a0.x, acc.x); acc.y = fmaf(p0, a0.y, acc.y);
        acc.z = fmaf(p0, b0.x, acc.z); acc.w = fmaf(p0, b0.y, acc.w);
        acc.x = fmaf(p1, a1.x, acc.x); acc.y = fmaf(p1, a1.y, acc.y);
        acc.z = fmaf(p1, b1.x, acc.z); acc.w = fmaf(p1, b1.y, acc.w);
        acc.x = fmaf(p2, a2.x, acc.x); acc.y = fmaf(p2, a2.y, acc.y);
        acc.z = fmaf(p2, b2.x, acc.z); acc.w = fmaf(p2, b2.y, acc.w);
        acc.x = fmaf(p3, a3.x, acc.x); acc.y = fmaf(p3, a3.y, acc.y);
        acc.z = fmaf(p3, b3.x, acc.z); acc.w = fmaf(p3, b3.y, acc.w);
    }

    // overflow tail (deg > DEG_CAP, ~1e-4 of nodes): exact, reads global
    float den_of = 0.0f;
    for (int j = jb + DEG_CAP; j < je; ++j) {
        int s = esrc[j];
        float e = ls_in[s] + ldv;
        e = (e >= 0.0f) ? e : NEG_SLOPE * e;
        float p = __expf(e - m);
        den_of += p;
        uint2 qv = *reinterpret_cast<const uint2*>(h16_in + (size_t)s * 64 + fl4);
        float2 va = __half22float2(*reinterpret_cast<__half2*>(&qv.x));
        float2 vb = __half22float2(*reinterpret_cast<__half2*>(&qv.y));
        acc.x = fmaf(p, va.x, acc.x);
        acc.y = fmaf(p, va.y, acc.y);
        acc.z = fmaf(p, vb.x, acc.z);
        acc.w = fmaf(p, vb.y, acc.w);
    }

    // self loop
    float e0s = lself + ldv;
    e0s = (e0s >= 0.0f) ? e0s : NEG_SLOPE * e0s;
    float p0s = __expf(e0s - m);
    float den = denl + den_of + p0s;
    acc.x = fmaf(p0s, sa.x, acc.x);
    acc.y = fmaf(p0s, sa.y, acc.y);
    acc.z = fmaf(p0s, sb.x, acc.z);
    acc.w = fmaf(p0s, sb.y, acc.w);

    const float4 b4 = *(const float4*)(bias + fl4);
    float inv = 1.0f / den;
    float4 o;
    o.x = acc.x * inv + b4.x;
    o.y = acc.y * inv + b4.y;
    o.z = acc.z * inv + b4.z;
    o.w = acc.w * inv + b4.w;
    o.x = (o.x > 0.0f) ? o.x : expm1f(o.x);
    o.y = (o.y > 0.0f) ? o.y : expm1f(o.y);
    o.z = (o.z > 0.0f) ? o.z : expm1f(o.z);
    o.w = (o.w > 0.0f) ? o.w : expm1f(o.w);

    // --- fused next-layer GEMM row: hn[f] = sum_k o[k] * Wn[k][f] ---
    // broadcast o via the group's dead sq region (exactly 16 float4), with
    // per-group skew so the 4 groups' reads land on distinct banks.
    float4* so = (float4*)sq;
    so[(fl + g) & 15] = o;
    float4 ha = make_float4(0.0f, 0.0f, 0.0f, 0.0f);
#pragma unroll
    for (int kk = 0; kk < 16; ++kk) {
        float4 ov = so[(kk + g) & 15];              // group-broadcast read
        const float4 w0 = *(const float4*)(sw + (4 * kk + 0) * 64 + fl4);
        const float4 w1 = *(const float4*)(sw + (4 * kk + 1) * 64 + fl4);
        const float4 w2 = *(const float4*)(sw + (4 * kk + 2) * 64 + fl4);
        const float4 w3 = *(const float4*)(sw + (4 * kk + 3) * 64 + fl4);
        ha.x = fmaf(ov.x, w0.x, ha.x); ha.y = fmaf(ov.x, w0.y, ha.y);
        ha.z = fmaf(ov.x, w0.z, ha.z); ha.w = fmaf(ov.x, w0.w, ha.w);
        ha.x = fmaf(ov.y, w1.x, ha.x); ha.y = fmaf(ov.y, w1.y, ha.y);
        ha.z = fmaf(ov.y, w1.z, ha.z); ha.w = fmaf(ov.y, w1.w, ha.w);
        ha.x = fmaf(ov.z, w2.x, ha.x); ha.y = fmaf(ov.z, w2.y, ha.y);
        ha.z = fmaf(ov.z, w2.z, ha.z); ha.w = fmaf(ov.z, w2.w, ha.w);
        ha.x = fmaf(ov.w, w3.x, ha.x); ha.y = fmaf(ov.w, w3.y, ha.y);
        ha.z = fmaf(ov.w, w3.z, ha.z); ha.w = fmaf(ov.w, w3.w, ha.w);
    }

    // store fp16 h row for next layer
    {
        __half2 plo = __floats2half2_rn(ha.x, ha.y);
        __half2 phi = __floats2half2_rn(ha.z, ha.w);
        uint2 pk;
        pk.x = *reinterpret_cast<unsigned*>(&plo);
        pk.y = *reinterpret_cast<unsigned*>(&phi);
        *reinterpret_cast<uint2*>(h16_out + (size_t)node * 64 + fl4) = pk;
    }
    // next-layer logits
    float4 as4 = *(const float4*)(asn + fl4);
    float4 ad4 = *(const float4*)(adn + fl4);
    float vs = ha.x * as4.x + ha.y * as4.y + ha.z * as4.z + ha.w * as4.w;
    float vd = ha.x * ad4.x + ha.y * ad4.y + ha.z * ad4.z + ha.w * ad4.w;
    vs += __shfl_xor(vs, 1, 64); vd += __shfl_xor(vd, 1, 64);
    vs += __shfl_xor(vs, 2, 64); vd += __shfl_xor(vd, 2, 64);
    vs += __shfl_xor(vs, 4, 64); vd += __shfl_xor(vd, 4, 64);
    vs += __shfl_xor(vs, 8, 64); vd += __shfl_xor(vd, 8, 64);
    if (fl == 0) { ls_out[node] = vs; ld_out[node] = vd; }
}

// ---------------------------------------------------------------------------
// Final-layer GAT (no fused gemm): fp16 gather, fp32 activation output.
// Same DEG_CAP=32 + skewed sq indexing.
// ---------------------------------------------------------------------------
__global__ __launch_bounds__(256) void gat_final_kernel(
        const __half* __restrict__ h16_in,
        const float* __restrict__ ls_in,
        const float* __restrict__ ld_in, const int* __restrict__ off,
        const int* __restrict__ esrc, const float* __restrict__ bias,
        float* __restrict__ hout, int n) {
    __shared__ int2 smq[16 * DEG_CAP];
    int t = threadIdx.x;
    int fl = t & 15;
    int g = t >> 4;
    int node = blockIdx.x * 16 + g;
    if (node >= n) return;
    int2* sq = smq + g * DEG_CAP;
    int fl4 = fl * 4;
    int sk4 = 4 * g;

    int jb = off[node];
    int je = off[node + 1];
    int deg = je - jb;
    int degc = (deg < DEG_CAP) ? deg : DEG_CAP;
    float ldv = ld_in[node];
    float lself = ls_in[node];

    float mm = lself;
    for (int c = fl; c < degc; c += 16) {
        int s = esrc[jb + c];
        float v = ls_in[s];
        sq[(c + sk4) & (DEG_CAP - 1)] = make_int2(s, __float_as_int(v));
        mm = fmaxf(mm, v);
    }
    for (int c = degc + fl; c < deg; c += 16) {
        mm = fmaxf(mm, ls_in[esrc[jb + c]]);
    }
    mm = fmaxf(mm, __shfl_xor(mm, 8, 64));
    mm = fmaxf(mm, __shfl_xor(mm, 4, 64));
    mm = fmaxf(mm, __shfl_xor(mm, 2, 64));
    mm = fmaxf(mm, __shfl_xor(mm, 1, 64));
    float mraw = mm + ldv;
    float m = (mraw >= 0.0f) ? mraw : NEG_SLOPE * mraw;

    float denl = 0.0f;
    for (int c = fl; c < degc; c += 16) {
        int ci = (c + sk4) & (DEG_CAP - 1);
        float e = __int_as_float(sq[ci].y) + ldv;
        e = (e >= 0.0f) ? e : NEG_SLOPE * e;
        float p = __expf(e - m);
        sq[ci].y = __float_as_int(p);
        denl += p;
    }
    int degc4 = (degc + 3) & ~3;
    if (fl < degc4 - degc) sq[(degc + fl + sk4) & (DEG_CAP - 1)] = make_int2(node, 0);

    denl += __shfl_xor(denl, 8, 64);
    denl += __shfl_xor(denl, 4, 64);
    denl += __shfl_xor(denl, 2, 64);
    denl += __shfl_xor(denl, 1, 64);

    uint2 qs = *reinterpret_cast<const uint2*>(h16_in + (size_t)node * 64 + fl4);
    float2 sa = __half22float2(*reinterpret_cast<__half2*>(&qs.x));
    float2 sb = __half22float2(*reinterpret_cast<__half2*>(&qs.y));

    float4 acc = make_float4(0.0f, 0.0f, 0.0f, 0.0f);
    for (int c = 0; c < degc4; c += 4) {
        int2 e0 = sq[(c + 0 + sk4) & (DEG_CAP - 1)];
        int2 e1 = sq[(c + 1 + sk4) & (DEG_CAP - 1)];
        int2 e2 = sq[(c + 2 + sk4) & (DEG_CAP - 1)];
        int2 e3 = sq[(c + 3 + sk4) & (DEG_CAP - 1)];
        uint2 q0 = *reinterpret_cast<const uint2*>(h16_in + (size_t)e0.x * 64 + fl4);
        uint2 q1 = *reinterpret_cast<const uint2*>(h16_in + (size_t)e1.x * 64 + fl4);
        uint2 q2 = *reinterpret_cast<const uint2*>(h16_in + (size_t)e2.x * 64 + fl4);
        uint2 q3 = *reinterpret_cast<const uint2*>(h16_in + (size_t)e3.x * 64 + fl4);
        float p0 = __int_as_float(e0.y), p1 = __int_as_float(e1.y);
        float p2 = __int_as_float(e2.y), p3 = __int_as_float(e3.y);
        float2 a0 = __half22float2(*reinterpret_cast<__half2*>(&q0.x));
        float2 b0 = __half22float2(*reinterpret_cast<__half2*>(&q0.y));
        float2 a1 = __half22float2(*reinterpret_cast<__half2*>(&q1.x));
        float2 b1 = __half22float2(*reinterpret_cast<__half2*>(&q1.y));
        float2 a2 = __half22float2(*reinterpret_cast<__half2*>(&q2.x));
        float2 b2 = __half22float2(*reinterpret_cast<__half2*>(&q2.y));
        float2 a3 = __half22float2(*reinterpret_cast<__half2*>(&q3.x));
        float2 b3 = __half22float2(*reinterpret_cast<__half2*>(&q3.y));
        acc.x = fmaf(p0, a0.x, acc.x); acc.y = fmaf(p0, a0.y, acc.y);
        acc.z = fmaf(p0, b0.x, acc.z); acc.w = fmaf(p0, b0.y, acc.w);
        acc.x = fmaf(p1, a1.x, acc.x); acc.y = fmaf(p1, a1.y, acc.y);
        acc.z = fmaf(p1, b1.x, acc.z); acc.w = fmaf(p1, b1.y, acc.w);
        acc.x = fmaf(p2, a2.x, acc.x); acc.y = fmaf(p2, a2.y, acc.y);
        acc.z = fmaf(p2, b2.x, acc.z); acc.w = fmaf(p2, b2.y, acc.w);
        acc.x = fmaf(p3, a3.x, acc.x); acc.y = fmaf(p3, a3.y, acc.y);
        acc.z = fmaf(p3, b3.x, acc.z); acc.w = fmaf(p3, b3.y, acc.w);
    }

    float den_of = 0.0f;
    for (int j = jb + DEG_CAP; j < je; ++j) {
        int s = esrc[j];
        float e = ls_in[s] + ldv;
        e = (e >= 0.0f) ? e : NEG_SLOPE * e;
        float p = __expf(e - m);
        den_of += p;
        uint2 qv = *reinterpret_cast<const uint2*>(h16_in + (size_t)s * 64 + fl4);
        float2 va = __half22float2(*reinterpret_cast<__half2*>(&qv.x));
        float2 vb = __half22float2(*reinterpret_cast<__half2*>(&qv.y));
        acc.x = fmaf(p, va.x, acc.x);
        acc.y = fmaf(p, va.y, acc.y);
        acc.z = fmaf(p, vb.x, acc.z);
        acc.w = fmaf(p, vb.y, acc.w);
    }

    float e0s = lself + ldv;
    e0s = (e0s >= 0.0f) ? e0s : NEG_SLOPE * e0s;
    float p0s = __expf(e0s - m);
    float den = denl + den_of + p0s;
    acc.x = fmaf(p0s, sa.x, acc.x);
    acc.y = fmaf(p0s, sa.y, acc.y);
    acc.z = fmaf(p0s, sb.x, acc.z);
    acc.w = fmaf(p0s, sb.y, acc.w);

    const float4 b4 = *(const float4*)(bias + fl4);
    float inv = 1.0f / den;
    float4 o;
    o.x = acc.x * inv + b4.x;
    o.y = acc.y * inv + b4.y;
    o.z = acc.z * inv + b4.z;
    o.w = acc.w * inv + b4.w;
    o.x = (o.x > 0.0f) ? o.x : expm1f(o.x);
    o.y = (o.y > 0.0f) ? o.y : expm1f(o.y);
    o.z = (o.z > 0.0f) ? o.z : expm1f(o.z);
    o.w = (o.w > 0.0f) ? o.w : expm1f(o.w);
    *(float4*)(hout + (size_t)node * 64 + fl4) = o;
}

// ---------------------------------------------------------------------------
// Global max pool: run-length (batch is sorted) + encoded atomicMax
// ---------------------------------------------------------------------------
__device__ __forceinline__ unsigned enc_f32(float f) {
    unsigned b = __float_as_uint(f);
    return (b & 0x80000000u) ? ~b : (b | 0x80000000u);
}

__global__ __launch_bounds__(256) void pool_kernel(const float* __restrict__ h,
                                                   const int* __restrict__ batch,
                                                   unsigned* __restrict__ genc, int n) {
    int lane = threadIdx.x & 63;
    int w = blockIdx.x * 4 + (threadIdx.x >> 6);
    int start = w * 64;
    if (start >= n) return;
    int end = start + 64; if (end > n) end = n;
    int cur = batch[start];
    float rm = -1e38f;
    for (int node = start; node < end; ++node) {
        int b = batch[node];                     // wave-uniform
        if (b != cur) {
            atomicMax(&genc[cur * 64 + lane], enc_f32(rm));
            cur = b;
            rm = -1e38f;
        }
        rm = fmaxf(rm, h[(size_t)node * 64 + lane]);
    }
    atomicMax(&genc[cur * 64 + lane], enc_f32(rm));
}

__global__ __launch_bounds__(64) void final_kernel(const unsigned* __restrict__ genc,
                                                   const float* __restrict__ linW,
                                                   const float* __restrict__ linb,
                                                   float* __restrict__ out) {
    int g = blockIdx.x;
    int lane = threadIdx.x;
    unsigned u = genc[g * 64 + lane];
    float v;
    if (u == 0u) {
        v = 0.0f;
    } else {
        unsigned b = (u & 0x80000000u) ? (u ^ 0x80000000u) : ~u;
        v = __uint_as_float(b);
    }
    float c0 = v * linW[lane * 2 + 0];
    float c1 = v * linW[lane * 2 + 1];
#pragma unroll
    for (int d = 32; d >= 1; d >>= 1) {
        c0 += __shfl_xor(c0, d, 64);
        c1 += __shfl_xor(c1, d, 64);
    }
    if (lane == 0) {
        out[g * 2 + 0] = c0 + linb[0];
        out[g * 2 + 1] = c1 + linb[1];
    }
}

// ---------------------------------------------------------------------------
// Launch
// ---------------------------------------------------------------------------
static inline size_t align_up(size_t v, size_t a) { return (v + a - 1) & ~(a - 1); }

extern "C" void kernel_launch(void* const* d_in, const int* in_sizes, int n_in,
                              void* d_out, int out_size, void* d_ws, size_t ws_size,
                              hipStream_t stream) {
    const float* x          = (const float*)d_in[0];
    const int*   edge_index = (const int*)d_in[1];
    const int*   batch      = (const int*)d_in[2];
    const float* W[5];
    const float* a_s[5];
    const float* a_d[5];
    const float* bias[5];
    for (int l = 0; l < 5; ++l) {
        W[l]    = (const float*)d_in[3 + 4 * l + 0];
        a_s[l]  = (const float*)d_in[3 + 4 * l + 1];
        a_d[l]  = (const float*)d_in[3 + 4 * l + 2];
        bias[l] = (const float*)d_in[3 + 4 * l + 3];
    }
    const float* linW = (const float*)d_in[23];
    const float* linb = (const float*)d_in[24];
    float* out = (float*)d_out;

    const int N = N_NODES;
    const int E = in_sizes[1] / 2;
    const int* srcp = edge_index;
    const int* dstp = edge_index + E;

    // workspace partition
    char* p = (char*)d_ws;
    int* bcount = (int*)p;        p += align_up((size_t)NBKT * 4, 256);
    int* bbase  = (int*)p;        p += align_up((size_t)(NBKT + 1) * 4, 256);
    int* bfill  = (int*)p;        p += align_up((size_t)NBKT * 4, 256);
    int* off    = (int*)p;        p += align_up((size_t)(N + 1) * 4, 256);
    int* esrc   = (int*)p;        p += align_up((size_t)E * 4, 256);
    float* lsA  = (float*)p;      p += align_up((size_t)N * 4, 256);
    float* ldA  = (float*)p;      p += align_up((size_t)N * 4, 256);
    float* lsB  = (float*)p;      p += align_up((size_t)N * 4, 256);
    float* ldB  = (float*)p;      p += align_up((size_t)N * 4, 256);
    __half* h16A = (__half*)p;    p += align_up((size_t)N * 64 * 2, 256);
    __half* h16B = (__half*)p;    p += align_up((size_t)N * 64 * 2, 256);
    float* h_a  = (float*)p;      p += align_up((size_t)N * 64 * 4, 256);
    unsigned* genc = (unsigned*)p; p += align_up((size_t)G_GRAPHS * 64 * 4, 256);

    // ebuck (E ints, 6.4MB, packed) aliases h_a (25.6MB): fully consumed by
    // bucket_csr before the final-layer gat writes h_a.
    int* ebuck = (int*)h_a;

    hipMemsetAsync(bcount, 0, (size_t)NBKT * 4, stream);
    hipMemsetAsync(genc, 0, (size_t)G_GRAPHS * 64 * 4, stream);

    int pb2 = (E + CHUNK_E - 1) / CHUNK_E;
    bucket_hist_kernel<<<pb2, 256, 0, stream>>>(dstp, bcount, E);
    bucket_scan_kernel<<<1, 256, 0, stream>>>(bcount, bbase, bfill, off, N);
    partition_kernel<<<pb2, 256, 0, stream>>>(srcp, dstp, bfill, ebuck, E);
    bucket_csr_kernel<<<NBKT, 256, 0, stream>>>(ebuck, bbase, off, esrc, N);

    int nb = (N + 15) / 16;   // 16 nodes per block
    int gt = (N + 127) / 128; // layer-0 GEMM: 128-node tiles

    // layer-0 GEMM -> set A
    gemm_tile_kernel<14, 16, 20><<<gt, 256, 0, stream>>>(
        x, W[0], a_s[0], a_d[0], h16A, lsA, ldA, N);
    // fused gat(l) + gemm(l+1), alternating buffers A->B->A->B->A
    gat_gemm_kernel<<<nb, 256, 0, stream>>>(
        h16A, lsA, ldA, off, esrc, bias[0], W[1], a_s[1], a_d[1],
        h16B, lsB, ldB, N);
    gat_gemm_kernel<<<nb, 256, 0, stream>>>(
        h16B, lsB, ldB, off, esrc, bias[1], W[2], a_s[2], a_d[2],
        h16A, lsA, ldA, N);
    gat_gemm_kernel<<<nb, 256, 0, stream>>>(
        h16A, lsA, ldA, off, esrc, bias[2], W[3], a_s[3], a_d[3],
        h16B, lsB, ldB, N);
    gat_gemm_kernel<<<nb, 256, 0, stream>>>(
        h16B, lsB, ldB, off, esrc, bias[3], W[4], a_s[4], a_d[4],
        h16A, lsA, ldA, N);
    // final layer: pure gat, fp32 out
    gat_final_kernel<<<nb, 256, 0, stream>>>(
        h16A, lsA, ldA, off, esrc, bias[4], h_a, N);

    int pw = (N + 63) / 64;
    int pbk = (pw + 3) / 4;
    pool_kernel<<<pbk, 256, 0, stream>>>(h_a, batch, genc, N);
    final_kernel<<<G_GRAPHS, 64, 0, stream>>>(genc, linW, linb, out);
}

// Round 16
// 425.681 us; speedup vs baseline: 1.1793x; 1.0037x over previous
//
#include <hip/hip_runtime.h>
#include <hip/hip_fp16.h>
#include <math.h>

#define N_NODES 100000
#define H_DIM 64
#define G_GRAPHS 512
#define NEG_SLOPE 0.2f

// bucketed CSR-build params
#define BSHIFT 9                         // 512 nodes per bucket
#define NBKT ((N_NODES + (1 << BSHIFT) - 1) >> BSHIFT)   // 196
#define CHUNK_E 4096                     // edges per partition block (16/thread)

#define DEG_CAP 32                       // staged edges/node; P(Poisson(16)>32)~1e-4, exact overflow path

// packed edge: src in bits [0,17), in-bucket dst in bits [17,26)
#define PK_SRC(v)  ((v) & 0x1FFFF)
#define PK_LD(v)   ((v) >> 17)

// v_dot2_f32_f16 availability (fp32-accumulating packed-fp16 dot)
#if defined(__has_builtin)
#if __has_builtin(__builtin_amdgcn_fdot2)
#define HAS_FDOT2 1
#endif
#endif
#ifndef HAS_FDOT2
#define HAS_FDOT2 0
#endif

#if HAS_FDOT2
typedef _Float16 h2_t __attribute__((ext_vector_type(2)));
__device__ __forceinline__ h2_t as_h2(unsigned u) {
    h2_t r; __builtin_memcpy(&r, &u, 4); return r;
}
#endif

// ---------------------------------------------------------------------------
// CSR build, bucket-first: no per-edge global atomics anywhere.
// ---------------------------------------------------------------------------

__global__ __launch_bounds__(256) void bucket_hist_kernel(const int* __restrict__ dst,
                                                          int* __restrict__ bcount, int E) {
    __shared__ int lh[NBKT];
    int t = threadIdx.x;
    for (int i = t; i < NBKT; i += 256) lh[i] = 0;
    __syncthreads();
    int base = blockIdx.x * CHUNK_E;
#pragma unroll
    for (int k = 0; k < 16; ++k) {
        int e = base + k * 256 + t;
        if (e < E) atomicAdd(&lh[dst[e] >> BSHIFT], 1);
    }
    __syncthreads();
    for (int i = t; i < NBKT; i += 256) {
        int c = lh[i];
        if (c) atomicAdd(&bcount[i], c);
    }
}

__global__ __launch_bounds__(256) void bucket_scan_kernel(const int* __restrict__ bcount,
                                                          int* __restrict__ bbase,
                                                          int* __restrict__ bfill,
                                                          int* __restrict__ off, int n) {
    __shared__ int sm[256];
    int t = threadIdx.x;
    sm[t] = (t < NBKT) ? bcount[t] : 0;
    __syncthreads();
    for (int d = 1; d < 256; d <<= 1) {
        int v = (t >= d) ? sm[t - d] : 0;
        __syncthreads();
        sm[t] += v;
        __syncthreads();
    }
    if (t < NBKT) {
        int ex = (t == 0) ? 0 : sm[t - 1];
        bbase[t] = ex;
        bfill[t] = ex;
    }
    if (t == 0) {
        bbase[NBKT] = sm[255];       // = E
        off[n] = sm[255];
    }
}

__global__ __launch_bounds__(256) void partition_kernel(const int* __restrict__ src,
                                                        const int* __restrict__ dst,
                                                        int* __restrict__ bfill,
                                                        int* __restrict__ ebuck, int E) {
    __shared__ int lh[NBKT];
    __shared__ int lbase[NBKT];
    int t = threadIdx.x;
    int base = blockIdx.x * CHUNK_E;
    for (int i = t; i < NBKT; i += 256) lh[i] = 0;
    __syncthreads();

    int pk[16], bk[16];
#pragma unroll
    for (int k = 0; k < 16; ++k) {
        int e = base + k * 256 + t;
        if (e < E) {
            int s = src[e];
            int d = dst[e];
            bk[k] = d >> BSHIFT;
            pk[k] = s | ((d & ((1 << BSHIFT) - 1)) << 17);
            atomicAdd(&lh[bk[k]], 1);
        } else {
            bk[k] = -1;
        }
    }
    __syncthreads();
    for (int i = t; i < NBKT; i += 256) {
        int c = lh[i];
        lbase[i] = c ? atomicAdd(&bfill[i], c) : 0;
        lh[i] = 0;
    }
    __syncthreads();
#pragma unroll
    for (int k = 0; k < 16; ++k) {
        if (bk[k] >= 0) {
            int r = atomicAdd(&lh[bk[k]], 1);
            ebuck[lbase[bk[k]] + r] = pk[k];
        }
    }
}

__global__ __launch_bounds__(256) void bucket_csr_kernel(const int* __restrict__ ebuck,
                                                         const int* __restrict__ bbase,
                                                         int* __restrict__ off,
                                                         int* __restrict__ esrc, int n) {
    __shared__ int cnt[512];
    __shared__ int loff[512];
    __shared__ int sm[256];
    int b = blockIdx.x;
    int t = threadIdx.x;
    int ebeg = bbase[b];
    int eend = bbase[b + 1];
    int nbeg = b << BSHIFT;
    int nloc = n - nbeg; if (nloc > 512) nloc = 512;

    cnt[t] = 0; cnt[t + 256] = 0;
    __syncthreads();
    for (int e = ebeg + t; e < eend; e += 256) {
        atomicAdd(&cnt[PK_LD(ebuck[e])], 1);
    }
    __syncthreads();
    int c0 = cnt[2 * t], c1 = cnt[2 * t + 1];
    sm[t] = c0 + c1;
    __syncthreads();
    for (int d = 1; d < 256; d <<= 1) {
        int v = (t >= d) ? sm[t - d] : 0;
        __syncthreads();
        sm[t] += v;
        __syncthreads();
    }
    int basep = (t == 0) ? 0 : sm[t - 1];
    loff[2 * t] = basep;
    loff[2 * t + 1] = basep + c0;
    cnt[2 * t] = 0; cnt[2 * t + 1] = 0;
    __syncthreads();
    for (int i = t; i < nloc; i += 256) off[nbeg + i] = ebeg + loff[i];
    for (int e = ebeg + t; e < eend; e += 256) {
        int v = ebuck[e];
        int d = PK_LD(v);
        int r = atomicAdd(&cnt[d], 1);
        esrc[ebeg + loff[d] + r] = PK_SRC(v);
    }
}

// ---------------------------------------------------------------------------
// Layer-0 GEMM + logits (round-4/5 structure, fp32 x input, fp16 h output).
// ---------------------------------------------------------------------------
template <int FIN, int FINP, int XSTR>
__global__ __launch_bounds__(256) void gemm_tile_kernel(
        const float* __restrict__ act, const float* __restrict__ W,
        const float* __restrict__ a_s, const float* __restrict__ a_d,
        __half* __restrict__ h16g,
        float* __restrict__ ls, float* __restrict__ ld,
        int n) {
    __shared__ float sx[128 * XSTR];
    __shared__ float sw[FINP * 64];
    int t = threadIdx.x;
    int tb = blockIdx.x * 128;
    int nrow = n - tb; if (nrow > 128) nrow = 128;

    {
        const float4* Wv = (const float4*)W;
        float4* swv = (float4*)sw;
        for (int i = t; i < FINP * 16; i += 256) {
            int k = i >> 4;
            swv[i] = (k < FIN) ? Wv[i] : make_float4(0.0f, 0.0f, 0.0f, 0.0f);
        }
    }
    {
        // scalar staging for unaligned FIN-float rows; pad cols [FIN,FINP) to 0
        int c = t & 15;
        for (int r = t >> 4; r < 128; r += 16) {
            float v = 0.0f;
            if (r < nrow && c < FIN) v = act[(size_t)(tb + r) * FIN + c];
            sx[r * XSTR + c] = v;
        }
    }
    __syncthreads();

    int f4 = t & 15;
    int ng = t >> 4;          // [0, 16)

    float4 acc[8];
#pragma unroll
    for (int i = 0; i < 8; ++i) acc[i] = make_float4(0.0f, 0.0f, 0.0f, 0.0f);

    for (int k4 = 0; k4 < FINP; k4 += 4) {
        float4 w0 = *(const float4*)(sw + (k4 + 0) * 64 + f4 * 4);
        float4 w1 = *(const float4*)(sw + (k4 + 1) * 64 + f4 * 4);
        float4 w2 = *(const float4*)(sw + (k4 + 2) * 64 + f4 * 4);
        float4 w3 = *(const float4*)(sw + (k4 + 3) * 64 + f4 * 4);
#pragma unroll
        for (int i = 0; i < 8; ++i) {
            float4 xv = *(const float4*)(sx + (ng + 16 * i) * XSTR + k4);
            acc[i].x = fmaf(xv.x, w0.x, acc[i].x);
            acc[i].y = fmaf(xv.x, w0.y, acc[i].y);
            acc[i].z = fmaf(xv.x, w0.z, acc[i].z);
            acc[i].w = fmaf(xv.x, w0.w, acc[i].w);
            acc[i].x = fmaf(xv.y, w1.x, acc[i].x);
            acc[i].y = fmaf(xv.y, w1.y, acc[i].y);
            acc[i].z = fmaf(xv.y, w1.z, acc[i].z);
            acc[i].w = fmaf(xv.y, w1.w, acc[i].w);
            acc[i].x = fmaf(xv.z, w2.x, acc[i].x);
            acc[i].y = fmaf(xv.z, w2.y, acc[i].y);
            acc[i].z = fmaf(xv.z, w2.z, acc[i].z);
            acc[i].w = fmaf(xv.z, w2.w, acc[i].w);
            acc[i].x = fmaf(xv.w, w3.x, acc[i].x);
            acc[i].y = fmaf(xv.w, w3.y, acc[i].y);
            acc[i].z = fmaf(xv.w, w3.z, acc[i].z);
            acc[i].w = fmaf(xv.w, w3.w, acc[i].w);
        }
    }

    float4 as4 = *(const float4*)(a_s + f4 * 4);
    float4 ad4 = *(const float4*)(a_d + f4 * 4);
#pragma unroll
    for (int i = 0; i < 8; ++i) {
        int r = ng + 16 * i;
        if (r < nrow) {
            int node = tb + r;
            __half2 plo = __floats2half2_rn(acc[i].x, acc[i].y);
            __half2 phi = __floats2half2_rn(acc[i].z, acc[i].w);
            uint2 pk;
            pk.x = *reinterpret_cast<unsigned*>(&plo);
            pk.y = *reinterpret_cast<unsigned*>(&phi);
            *reinterpret_cast<uint2*>(h16g + (size_t)node * 64 + f4 * 4) = pk;
            float vs = acc[i].x * as4.x + acc[i].y * as4.y +
                       acc[i].z * as4.z + acc[i].w * as4.w;
            float vd = acc[i].x * ad4.x + acc[i].y * ad4.y +
                       acc[i].z * ad4.z + acc[i].w * ad4.w;
            vs += __shfl_xor(vs, 1, 64); vd += __shfl_xor(vd, 1, 64);
            vs += __shfl_xor(vs, 2, 64); vd += __shfl_xor(vd, 2, 64);
            vs += __shfl_xor(vs, 4, 64); vd += __shfl_xor(vd, 4, 64);
            vs += __shfl_xor(vs, 8, 64); vd += __shfl_xor(vd, 8, 64);
            if (f4 == 0) { ls[node] = vs; ld[node] = vd; }
        }
    }
}

// ---------------------------------------------------------------------------
// FUSED: gat(layer l) + gemm(layer l+1) + logits(layer l+1).
// v16: fused GEMM via v_dot2_f32_f16 (fp16 packed operands, fp32 accumulate):
// W staged as half2 pairs along k (8KB), o packed to 2x half2 per lane and
// shared via the skewed so slots. Halves the GEMM's VALU instruction count.
// Fallback (no fdot2 builtin): round-15 fp32 path.
// ---------------------------------------------------------------------------
__global__ __launch_bounds__(256) void gat_gemm_kernel(
        const __half* __restrict__ h16_in, const float* __restrict__ ls_in,
        const float* __restrict__ ld_in, const int* __restrict__ off,
        const int* __restrict__ esrc, const float* __restrict__ bias,
        const float* __restrict__ Wn, const float* __restrict__ asn,
        const float* __restrict__ adn,
        __half* __restrict__ h16_out, float* __restrict__ ls_out,
        float* __restrict__ ld_out, int n) {
#if HAS_FDOT2
    __shared__ unsigned sw2[32 * 64];        // 8 KB: W packed half2 along k
#else
    __shared__ float sw[64 * 64];            // 16 KB: W(l+1) fp32
#endif
    __shared__ int2 smq[16 * DEG_CAP];       // 4 KB: (src, ls->p) per group
    int t = threadIdx.x;
    // stage W with ALL threads (before any early return)
#if HAS_FDOT2
    for (int i = t; i < 32 * 64; i += 256) {
        int k2 = i >> 6, f = i & 63;
        float w0 = Wn[(2 * k2) * 64 + f];
        float w1 = Wn[(2 * k2 + 1) * 64 + f];
        __half2 wp = __floats2half2_rn(w0, w1);
        sw2[i] = *reinterpret_cast<unsigned*>(&wp);
    }
#else
    {
        const float4* Wv = (const float4*)Wn;
        float4* swv = (float4*)sw;
        for (int i = t; i < 64 * 16; i += 256) swv[i] = Wv[i];
    }
#endif
    __syncthreads();   // no barriers after this point (intra-group ops only)

    int fl = t & 15;
    int g = t >> 4;
    int node = blockIdx.x * 16 + g;
    if (node >= n) return;
    int2* sq = smq + g * DEG_CAP;
    int fl4 = fl * 4;
    int sk4 = 4 * g;                          // per-group bank skew

    int jb = off[node];
    int je = off[node + 1];
    int deg = je - jb;
    int degc = (deg < DEG_CAP) ? deg : DEG_CAP;
    float ldv = ld_in[node];
    float lself = ls_in[node];

    // pass 1: gather ls, stage (skewed), running max (leaky is monotone)
    float mm = lself;
    for (int c = fl; c < degc; c += 16) {
        int s = esrc[jb + c];
        float v = ls_in[s];
        sq[(c + sk4) & (DEG_CAP - 1)] = make_int2(s, __float_as_int(v));
        mm = fmaxf(mm, v);
    }
    for (int c = degc + fl; c < deg; c += 16) {
        mm = fmaxf(mm, ls_in[esrc[jb + c]]);
    }
    mm = fmaxf(mm, __shfl_xor(mm, 8, 64));
    mm = fmaxf(mm, __shfl_xor(mm, 4, 64));
    mm = fmaxf(mm, __shfl_xor(mm, 2, 64));
    mm = fmaxf(mm, __shfl_xor(mm, 1, 64));
    float mraw = mm + ldv;
    float m = (mraw >= 0.0f) ? mraw : NEG_SLOPE * mraw;

    // pass 2: ls -> p in LDS, lane-partial den
    float denl = 0.0f;
    for (int c = fl; c < degc; c += 16) {
        int ci = (c + sk4) & (DEG_CAP - 1);
        float e = __int_as_float(sq[ci].y) + ldv;
        e = (e >= 0.0f) ? e : NEG_SLOPE * e;
        float p = __expf(e - m);
        sq[ci].y = __float_as_int(p);
        denl += p;
    }
    int degc4 = (degc + 3) & ~3;
    if (fl < degc4 - degc) sq[(degc + fl + sk4) & (DEG_CAP - 1)] = make_int2(node, 0);

    denl += __shfl_xor(denl, 8, 64);
    denl += __shfl_xor(denl, 4, 64);
    denl += __shfl_xor(denl, 2, 64);
    denl += __shfl_xor(denl, 1, 64);

    // self row early
    uint2 qs = *reinterpret_cast<const uint2*>(h16_in + (size_t)node * 64 + fl4);
    float2 sa = __half22float2(*reinterpret_cast<__half2*>(&qs.x));
    float2 sb = __half22float2(*reinterpret_cast<__half2*>(&qs.y));

    // gather loop: 4 independent 128B fp16 row loads in flight per group
    float4 acc = make_float4(0.0f, 0.0f, 0.0f, 0.0f);
    for (int c = 0; c < degc4; c += 4) {
        int2 e0 = sq[(c + 0 + sk4) & (DEG_CAP - 1)];
        int2 e1 = sq[(c + 1 + sk4) & (DEG_CAP - 1)];
        int2 e2 = sq[(c + 2 + sk4) & (DEG_CAP - 1)];
        int2 e3 = sq[(c + 3 + sk4) & (DEG_CAP - 1)];
        uint2 q0 = *reinterpret_cast<const uint2*>(h16_in + (size_t)e0.x * 64 + fl4);
        uint2 q1 = *reinterpret_cast<const uint2*>(h16_in + (size_t)e1.x * 64 + fl4);
        uint2 q2 = *reinterpret_cast<const uint2*>(h16_in + (size_t)e2.x * 64 + fl4);
        uint2 q3 = *reinterpret_cast<const uint2*>(h16_in + (size_t)e3.x * 64 + fl4);
        float p0 = __int_as_float(e0.y), p1 = __int_as_float(e1.y);
        float p2 = __int_as_float(e2.y), p3 = __int_as_float(e3.y);
        float2 a0 = __half22float2(*reinterpret_cast<__half2*>(&q0.x));
        float2 b0 = __half22float2(*reinterpret_cast<__half2*>(&q0.y));
        float2 a1 = __half22float2(*reinterpret_cast<__half2*>(&q1.x));
        float2 b1 = __half22float2(*reinterpret_cast<__half2*>(&q1.y));
        float2 a2 = __half22float2(*reinterpret_cast<__half2*>(&q2.x));
        float2 b2 = __half22float2(*reinterpret_cast<__half2*>(&q2.y));
        float2 a3 = __half22float2(*reinterpret_cast<__half2*>(&q3.x));
        float2 b3 = __half22float2(*reinterpret_cast<__half2*>(&q3.y));
        acc.x = fmaf(p0, a0.x, acc.x); acc.y = fmaf(p0, a0.y, acc.y);
        acc.z = fmaf(p0, b0.x, acc.z); acc.w = fmaf(p0, b0.y, acc.w);
        acc.x = fmaf(p1, a1.x, acc.x); acc.y = fmaf(p1, a1.y, acc.y);
        acc.z = fmaf(p1, b1.x, acc.z); acc.w = fmaf(p1, b1.y, acc.w);
        acc.x = fmaf(p2, a2.x, acc.x); acc.y = fmaf(p2, a2.y, acc.y);
        acc.z = fmaf(p2, b2.x, acc.z); acc.w = fmaf(p2, b2.y, acc.w);
        acc.x = fmaf(p3, a3.x, acc.x); acc.y = fmaf(p3, a3.y, acc.y);
        acc.z = fmaf(p3, b3.x, acc.z); acc.w = fmaf(p3, b3.y, acc.w);
    }

    // overflow tail (deg > DEG_CAP, ~1e-4 of nodes): exact, reads global
    float den_of = 0.0f;
    for (int j = jb + DEG_CAP; j < je; ++j) {
        int s = esrc[j];
        float e = ls_in[s] + ldv;
        e = (e >= 0.0f) ? e : NEG_SLOPE * e;
        float p = __expf(e - m);
        den_of += p;
        uint2 qv = *reinterpret_cast<const uint2*>(h16_in + (size_t)s * 64 + fl4);
        float2 va = __half22float2(*reinterpret_cast<__half2*>(&qv.x));
        float2 vb = __half22float2(*reinterpret_cast<__half2*>(&qv.y));
        acc.x = fmaf(p, va.x, acc.x);
        acc.y = fmaf(p, va.y, acc.y);
        acc.z = fmaf(p, vb.x, acc.z);
        acc.w = fmaf(p, vb.y, acc.w);
    }

    // self loop
    float e0s = lself + ldv;
    e0s = (e0s >= 0.0f) ? e0s : NEG_SLOPE * e0s;
    float p0s = __expf(e0s - m);
    float den = denl + den_of + p0s;
    acc.x = fmaf(p0s, sa.x, acc.x);
    acc.y = fmaf(p0s, sa.y, acc.y);
    acc.z = fmaf(p0s, sb.x, acc.z);
    acc.w = fmaf(p0s, sb.y, acc.w);

    const float4 b4 = *(const float4*)(bias + fl4);
    float inv = 1.0f / den;
    float4 o;
    o.x = acc.x * inv + b4.x;
    o.y = acc.y * inv + b4.y;
    o.z = acc.z * inv + b4.z;
    o.w = acc.w * inv + b4.w;
    o.x = (o.x > 0.0f) ? o.x : expm1f(o.x);
    o.y = (o.y > 0.0f) ? o.y : expm1f(o.y);
    o.z = (o.z > 0.0f) ? o.z : expm1f(o.z);
    o.w = (o.w > 0.0f) ? o.w : expm1f(o.w);

    // --- fused next-layer GEMM row: hn[f] = sum_k o[k] * Wn[k][f] ---
    float4 ha = make_float4(0.0f, 0.0f, 0.0f, 0.0f);
#if HAS_FDOT2
    // pack o to 2x half2 (matches unfused fp16-activation semantics) and
    // share via the group's dead sq region (skewed slots, 8B each).
    {
        __half2 plo = __floats2half2_rn(o.x, o.y);
        __half2 phi = __floats2half2_rn(o.z, o.w);
        uint2 pk;
        pk.x = *reinterpret_cast<unsigned*>(&plo);
        pk.y = *reinterpret_cast<unsigned*>(&phi);
        uint2* so16 = (uint2*)sq;
        so16[(fl + g) & 15] = pk;
#pragma unroll
        for (int kk = 0; kk < 16; ++kk) {
            uint2 ov = so16[(kk + g) & 15];     // o[4kk..4kk+3] as 2x half2
            h2_t o01 = as_h2(ov.x);
            h2_t o23 = as_h2(ov.y);
            // W pair rows k2 = 2kk (k=4kk,4kk+1) and 2kk+1 (k=4kk+2,4kk+3)
            const uint4 wA = *reinterpret_cast<const uint4*>(sw2 + (2 * kk) * 64 + fl4);
            const uint4 wB = *reinterpret_cast<const uint4*>(sw2 + (2 * kk + 1) * 64 + fl4);
            ha.x = __builtin_amdgcn_fdot2(o01, as_h2(wA.x), ha.x, false);
            ha.y = __builtin_amdgcn_fdot2(o01, as_h2(wA.y), ha.y, false);
            ha.z = __builtin_amdgcn_fdot2(o01, as_h2(wA.z), ha.z, false);
            ha.w = __builtin_amdgcn_fdot2(o01, as_h2(wA.w), ha.w, false);
            ha.x = __builtin_amdgcn_fdot2(o23, as_h2(wB.x), ha.x, false);
            ha.y = __builtin_amdgcn_fdot2(o23, as_h2(wB.y), ha.y, false);
            ha.z = __builtin_amdgcn_fdot2(o23, as_h2(wB.z), ha.z, false);
            ha.w = __builtin_amdgcn_fdot2(o23, as_h2(wB.w), ha.w, false);
        }
    }
#else
    {
        float4* so = (float4*)sq;
        so[(fl + g) & 15] = o;
#pragma unroll
        for (int kk = 0; kk < 16; ++kk) {
            float4 ov = so[(kk + g) & 15];
            const float4 w0 = *(const float4*)(sw + (4 * kk + 0) * 64 + fl4);
            const float4 w1 = *(const float4*)(sw + (4 * kk + 1) * 64 + fl4);
            const float4 w2 = *(const float4*)(sw + (4 * kk + 2) * 64 + fl4);
            const float4 w3 = *(const float4*)(sw + (4 * kk + 3) * 64 + fl4);
            ha.x = fmaf(ov.x, w0.x, ha.x); ha.y = fmaf(ov.x, w0.y, ha.y);
            ha.z = fmaf(ov.x, w0.z, ha.z); ha.w = fmaf(ov.x, w0.w, ha.w);
            ha.x = fmaf(ov.y, w1.x, ha.x); ha.y = fmaf(ov.y, w1.y, ha.y);
            ha.z = fmaf(ov.y, w1.z, ha.z); ha.w = fmaf(ov.y, w1.w, ha.w);
            ha.x = fmaf(ov.z, w2.x, ha.x); ha.y = fmaf(ov.z, w2.y, ha.y);
            ha.z = fmaf(ov.z, w2.z, ha.z); ha.w = fmaf(ov.z, w2.w, ha.w);
            ha.x = fmaf(ov.w, w3.x, ha.x); ha.y = fmaf(ov.w, w3.y, ha.y);
            ha.z = fmaf(ov.w, w3.z, ha.z); ha.w = fmaf(ov.w, w3.w, ha.w);
        }
    }
#endif

    // store fp16 h row for next layer
    {
        __half2 plo = __floats2half2_rn(ha.x, ha.y);
        __half2 phi = __floats2half2_rn(ha.z, ha.w);
        uint2 pk;
        pk.x = *reinterpret_cast<unsigned*>(&plo);
        pk.y = *reinterpret_cast<unsigned*>(&phi);
        *reinterpret_cast<uint2*>(h16_out + (size_t)node * 64 + fl4) = pk;
    }
    // next-layer logits
    float4 as4 = *(const float4*)(asn + fl4);
    float4 ad4 = *(const float4*)(adn + fl4);
    float vs = ha.x * as4.x + ha.y * as4.y + ha.z * as4.z + ha.w * as4.w;
    float vd = ha.x * ad4.x + ha.y * ad4.y + ha.z * ad4.z + ha.w * ad4.w;
    vs += __shfl_xor(vs, 1, 64); vd += __shfl_xor(vd, 1, 64);
    vs += __shfl_xor(vs, 2, 64); vd += __shfl_xor(vd, 2, 64);
    vs += __shfl_xor(vs, 4, 64); vd += __shfl_xor(vd, 4, 64);
    vs += __shfl_xor(vs, 8, 64); vd += __shfl_xor(vd, 8, 64);
    if (fl == 0) { ls_out[node] = vs; ld_out[node] = vd; }
}

// ---------------------------------------------------------------------------
// Final-layer GAT (no fused gemm): fp16 gather, fp32 activation output.
// ---------------------------------------------------------------------------
__global__ __launch_bounds__(256) void gat_final_kernel(
        const __half* __restrict__ h16_in,
        const float* __restrict__ ls_in,
        const float* __restrict__ ld_in, const int* __restrict__ off,
        const int* __restrict__ esrc, const float* __restrict__ bias,
        float* __restrict__ hout, int n) {
    __shared__ int2 smq[16 * DEG_CAP];
    int t = threadIdx.x;
    int fl = t & 15;
    int g = t >> 4;
    int node = blockIdx.x * 16 + g;
    if (node >= n) return;
    int2* sq = smq + g * DEG_CAP;
    int fl4 = fl * 4;
    int sk4 = 4 * g;

    int jb = off[node];
    int je = off[node + 1];
    int deg = je - jb;
    int degc = (deg < DEG_CAP) ? deg : DEG_CAP;
    float ldv = ld_in[node];
    float lself = ls_in[node];

    float mm = lself;
    for (int c = fl; c < degc; c += 16) {
        int s = esrc[jb + c];
        float v = ls_in[s];
        sq[(c + sk4) & (DEG_CAP - 1)] = make_int2(s, __float_as_int(v));
        mm = fmaxf(mm, v);
    }
    for (int c = degc + fl; c < deg; c += 16) {
        mm = fmaxf(mm, ls_in[esrc[jb + c]]);
    }
    mm = fmaxf(mm, __shfl_xor(mm, 8, 64));
    mm = fmaxf(mm, __shfl_xor(mm, 4, 64));
    mm = fmaxf(mm, __shfl_xor(mm, 2, 64));
    mm = fmaxf(mm, __shfl_xor(mm, 1, 64));
    float mraw = mm + ldv;
    float m = (mraw >= 0.0f) ? mraw : NEG_SLOPE * mraw;

    float denl = 0.0f;
    for (int c = fl; c < degc; c += 16) {
        int ci = (c + sk4) & (DEG_CAP - 1);
        float e = __int_as_float(sq[ci].y) + ldv;
        e = (e >= 0.0f) ? e : NEG_SLOPE * e;
        float p = __expf(e - m);
        sq[ci].y = __float_as_int(p);
        denl += p;
    }
    int degc4 = (degc + 3) & ~3;
    if (fl < degc4 - degc) sq[(degc + fl + sk4) & (DEG_CAP - 1)] = make_int2(node, 0);

    denl += __shfl_xor(denl, 8, 64);
    denl += __shfl_xor(denl, 4, 64);
    denl += __shfl_xor(denl, 2, 64);
    denl += __shfl_xor(denl, 1, 64);

    uint2 qs = *reinterpret_cast<const uint2*>(h16_in + (size_t)node * 64 + fl4);
    float2 sa = __half22float2(*reinterpret_cast<__half2*>(&qs.x));
    float2 sb = __half22float2(*reinterpret_cast<__half2*>(&qs.y));

    float4 acc = make_float4(0.0f, 0.0f, 0.0f, 0.0f);
    for (int c = 0; c < degc4; c += 4) {
        int2 e0 = sq[(c + 0 + sk4) & (DEG_CAP - 1)];
        int2 e1 = sq[(c + 1 + sk4) & (DEG_CAP - 1)];
        int2 e2 = sq[(c + 2 + sk4) & (DEG_CAP - 1)];
        int2 e3 = sq[(c + 3 + sk4) & (DEG_CAP - 1)];
        uint2 q0 = *reinterpret_cast<const uint2*>(h16_in + (size_t)e0.x * 64 + fl4);
        uint2 q1 = *reinterpret_cast<const uint2*>(h16_in + (size_t)e1.x * 64 + fl4);
        uint2 q2 = *reinterpret_cast<const uint2*>(h16_in + (size_t)e2.x * 64 + fl4);
        uint2 q3 = *reinterpret_cast<const uint2*>(h16_in + (size_t)e3.x * 64 + fl4);
        float p0 = __int_as_float(e0.y), p1 = __int_as_float(e1.y);
        float p2 = __int_as_float(e2.y), p3 = __int_as_float(e3.y);
        float2 a0 = __half22float2(*reinterpret_cast<__half2*>(&q0.x));
        float2 b0 = __half22float2(*reinterpret_cast<__half2*>(&q0.y));
        float2 a1 = __half22float2(*reinterpret_cast<__half2*>(&q1.x));
        float2 b1 = __half22float2(*reinterpret_cast<__half2*>(&q1.y));
        float2 a2 = __half22float2(*reinterpret_cast<__half2*>(&q2.x));
        float2 b2 = __half22float2(*reinterpret_cast<__half2*>(&q2.y));
        float2 a3 = __half22float2(*reinterpret_cast<__half2*>(&q3.x));
        float2 b3 = __half22float2(*reinterpret_cast<__half2*>(&q3.y));
        acc.x = fmaf(p0, a0.x, acc.x); acc.y = fmaf(p0, a0.y, acc.y);
        acc.z = fmaf(p0, b0.x, acc.z); acc.w = fmaf(p0, b0.y, acc.w);
        acc.x = fmaf(p1, a1.x, acc.x); acc.y = fmaf(p1, a1.y, acc.y);
        acc.z = fmaf(p1, b1.x, acc.z); acc.w = fmaf(p1, b1.y, acc.w);
        acc.x = fmaf(p2, a2.x, acc.x); acc.y = fmaf(p2, a2.y, acc.y);
        acc.z = fmaf(p2, b2.x, acc.z); acc.w = fmaf(p2, b2.y, acc.w);
        acc.x = fmaf(p3, a3.x, acc.x); acc.y = fmaf(p3, a3.y, acc.y);
        acc.z = fmaf(p3, b3.x, acc.z); acc.w = fmaf(p3, b3.y, acc.w);
    }

    float den_of = 0.0f;
    for (int j = jb + DEG_CAP; j < je; ++j) {
        int s = esrc[j];
        float e = ls_in[s] + ldv;
        e = (e >= 0.0f) ? e : NEG_SLOPE * e;
        float p = __expf(e - m);
        den_of += p;
        uint2 qv = *reinterpret_cast<const uint2*>(h16_in + (size_t)s * 64 + fl4);
        float2 va = __half22float2(*reinterpret_cast<__half2*>(&qv.x));
        float2 vb = __half22float2(*reinterpret_cast<__half2*>(&qv.y));
        acc.x = fmaf(p, va.x, acc.x);
        acc.y = fmaf(p, va.y, acc.y);
        acc.z = fmaf(p, vb.x, acc.z);
        acc.w = fmaf(p, vb.y, acc.w);
    }

    float e0s = lself + ldv;
    e0s = (e0s >= 0.0f) ? e0s : NEG_SLOPE * e0s;
    float p0s = __expf(e0s - m);
    float den = denl + den_of + p0s;
    acc.x = fmaf(p0s, sa.x, acc.x);
    acc.y = fmaf(p0s, sa.y, acc.y);
    acc.z = fmaf(p0s, sb.x, acc.z);
    acc.w = fmaf(p0s, sb.y, acc.w);

    const float4 b4 = *(const float4*)(bias + fl4);
    float inv = 1.0f / den;
    float4 o;
    o.x = acc.x * inv + b4.x;
    o.y = acc.y * inv + b4.y;
    o.z = acc.z * inv + b4.z;
    o.w = acc.w * inv + b4.w;
    o.x = (o.x > 0.0f) ? o.x : expm1f(o.x);
    o.y = (o.y > 0.0f) ? o.y : expm1f(o.y);
    o.z = (o.z > 0.0f) ? o.z : expm1f(o.z);
    o.w = (o.w > 0.0f) ? o.w : expm1f(o.w);
    *(float4*)(hout + (size_t)node * 64 + fl4) = o;
}

// ---------------------------------------------------------------------------
// Global max pool: run-length (batch is sorted) + encoded atomicMax
// ---------------------------------------------------------------------------
__device__ __forceinline__ unsigned enc_f32(float f) {
    unsigned b = __float_as_uint(f);
    return (b & 0x80000000u) ? ~b : (b | 0x80000000u);
}

__global__ __launch_bounds__(256) void pool_kernel(const float* __restrict__ h,
                                                   const int* __restrict__ batch,
                                                   unsigned* __restrict__ genc, int n) {
    int lane = threadIdx.x & 63;
    int w = blockIdx.x * 4 + (threadIdx.x >> 6);
    int start = w * 64;
    if (start >= n) return;
    int end = start + 64; if (end > n) end = n;
    int cur = batch[start];
    float rm = -1e38f;
    for (int node = start; node < end; ++node) {
        int b = batch[node];                     // wave-uniform
        if (b != cur) {
            atomicMax(&genc[cur * 64 + lane], enc_f32(rm));
            cur = b;
            rm = -1e38f;
        }
        rm = fmaxf(rm, h[(size_t)node * 64 + lane]);
    }
    atomicMax(&genc[cur * 64 + lane], enc_f32(rm));
}

__global__ __launch_bounds__(64) void final_kernel(const unsigned* __restrict__ genc,
                                                   const float* __restrict__ linW,
                                                   const float* __restrict__ linb,
                                                   float* __restrict__ out) {
    int g = blockIdx.x;
    int lane = threadIdx.x;
    unsigned u = genc[g * 64 + lane];
    float v;
    if (u == 0u) {
        v = 0.0f;
    } else {
        unsigned b = (u & 0x80000000u) ? (u ^ 0x80000000u) : ~u;
        v = __uint_as_float(b);
    }
    float c0 = v * linW[lane * 2 + 0];
    float c1 = v * linW[lane * 2 + 1];
#pragma unroll
    for (int d = 32; d >= 1; d >>= 1) {
        c0 += __shfl_xor(c0, d, 64);
        c1 += __shfl_xor(c1, d, 64);
    }
    if (lane == 0) {
        out[g * 2 + 0] = c0 + linb[0];
        out[g * 2 + 1] = c1 + linb[1];
    }
}

// ---------------------------------------------------------------------------
// Launch
// ---------------------------------------------------------------------------
static inline size_t align_up(size_t v, size_t a) { return (v + a - 1) & ~(a - 1); }

extern "C" void kernel_launch(void* const* d_in, const int* in_sizes, int n_in,
                              void* d_out, int out_size, void* d_ws, size_t ws_size,
                              hipStream_t stream) {
    const float* x          = (const float*)d_in[0];
    const int*   edge_index = (const int*)d_in[1];
    const int*   batch      = (const int*)d_in[2];
    const float* W[5];
    const float* a_s[5];
    const float* a_d[5];
    const float* bias[5];
    for (int l = 0; l < 5; ++l) {
        W[l]    = (const float*)d_in[3 + 4 * l + 0];
        a_s[l]  = (const float*)d_in[3 + 4 * l + 1];
        a_d[l]  = (const float*)d_in[3 + 4 * l + 2];
        bias[l] = (const float*)d_in[3 + 4 * l + 3];
    }
    const float* linW = (const float*)d_in[23];
    const float* linb = (const float*)d_in[24];
    float* out = (float*)d_out;

    const int N = N_NODES;
    const int E = in_sizes[1] / 2;
    const int* srcp = edge_index;
    const int* dstp = edge_index + E;

    // workspace partition
    char* p = (char*)d_ws;
    int* bcount = (int*)p;        p += align_up((size_t)NBKT * 4, 256);
    int* bbase  = (int*)p;        p += align_up((size_t)(NBKT + 1) * 4, 256);
    int* bfill  = (int*)p;        p += align_up((size_t)NBKT * 4, 256);
    int* off    = (int*)p;        p += align_up((size_t)(N + 1) * 4, 256);
    int* esrc   = (int*)p;        p += align_up((size_t)E * 4, 256);
    float* lsA  = (float*)p;      p += align_up((size_t)N * 4, 256);
    float* ldA  = (float*)p;      p += align_up((size_t)N * 4, 256);
    float* lsB  = (float*)p;      p += align_up((size_t)N * 4, 256);
    float* ldB  = (float*)p;      p += align_up((size_t)N * 4, 256);
    __half* h16A = (__half*)p;    p += align_up((size_t)N * 64 * 2, 256);
    __half* h16B = (__half*)p;    p += align_up((size_t)N * 64 * 2, 256);
    float* h_a  = (float*)p;      p += align_up((size_t)N * 64 * 4, 256);
    unsigned* genc = (unsigned*)p; p += align_up((size_t)G_GRAPHS * 64 * 4, 256);

    // ebuck (E ints, 6.4MB, packed) aliases h_a (25.6MB): fully consumed by
    // bucket_csr before the final-layer gat writes h_a.
    int* ebuck = (int*)h_a;

    hipMemsetAsync(bcount, 0, (size_t)NBKT * 4, stream);
    hipMemsetAsync(genc, 0, (size_t)G_GRAPHS * 64 * 4, stream);

    int pb2 = (E + CHUNK_E - 1) / CHUNK_E;
    bucket_hist_kernel<<<pb2, 256, 0, stream>>>(dstp, bcount, E);
    bucket_scan_kernel<<<1, 256, 0, stream>>>(bcount, bbase, bfill, off, N);
    partition_kernel<<<pb2, 256, 0, stream>>>(srcp, dstp, bfill, ebuck, E);
    bucket_csr_kernel<<<NBKT, 256, 0, stream>>>(ebuck, bbase, off, esrc, N);

    int nb = (N + 15) / 16;   // 16 nodes per block
    int gt = (N + 127) / 128; // layer-0 GEMM: 128-node tiles

    // layer-0 GEMM -> set A
    gemm_tile_kernel<14, 16, 20><<<gt, 256, 0, stream>>>(
        x, W[0], a_s[0], a_d[0], h16A, lsA, ldA, N);
    // fused gat(l) + gemm(l+1), alternating buffers A->B->A->B->A
    gat_gemm_kernel<<<nb, 256, 0, stream>>>(
        h16A, lsA, ldA, off, esrc, bias[0], W[1], a_s[1], a_d[1],
        h16B, lsB, ldB, N);
    gat_gemm_kernel<<<nb, 256, 0, stream>>>(
        h16B, lsB, ldB, off, esrc, bias[1], W[2], a_s[2], a_d[2],
        h16A, lsA, ldA, N);
    gat_gemm_kernel<<<nb, 256, 0, stream>>>(
        h16A, lsA, ldA, off, esrc, bias[2], W[3], a_s[3], a_d[3],
        h16B, lsB, ldB, N);
    gat_gemm_kernel<<<nb, 256, 0, stream>>>(
        h16B, lsB, ldB, off, esrc, bias[3], W[4], a_s[4], a_d[4],
        h16A, lsA, ldA, N);
    // final layer: pure gat, fp32 out
    gat_final_kernel<<<nb, 256, 0, stream>>>(
        h16A, lsA, ldA, off, esrc, bias[4], h_a, N);

    int pw = (N + 63) / 64;
    int pbk = (pw + 3) / 4;
    pool_kernel<<<pbk, 256, 0, stream>>>(h_a, batch, genc, N);
    final_kernel<<<G_GRAPHS, 64, 0, stream>>>(genc, linW, linb, out);
}

// Round 17
// 400.337 us; speedup vs baseline: 1.2540x; 1.0633x over previous
//
#include <hip/hip_runtime.h>
#include <hip/hip_fp16.h>
#include <math.h>

#define N_NODES 100000
#define H_DIM 64
#define G_GRAPHS 512
#define NEG_SLOPE 0.2f

// bucketed CSR-build params
#define BSHIFT 9                         // 512 nodes per bucket
#define NBKT ((N_NODES + (1 << BSHIFT) - 1) >> BSHIFT)   // 196
#define CHUNK_E 4096                     // edges per partition block (16/thread)

#define DEG_CAP 32                       // staged edges/node; P(Poisson(16)>32)~1e-4, exact overflow path

// packed edge: src in bits [0,17), in-bucket dst in bits [17,26)
#define PK_SRC(v)  ((v) & 0x1FFFF)
#define PK_LD(v)   ((v) >> 17)

// v_dot2_f32_f16 availability (fp32-accumulating packed-fp16 dot)
#if defined(__has_builtin)
#if __has_builtin(__builtin_amdgcn_fdot2)
#define HAS_FDOT2 1
#endif
#endif
#ifndef HAS_FDOT2
#define HAS_FDOT2 0
#endif

#if HAS_FDOT2
typedef _Float16 h2_t __attribute__((ext_vector_type(2)));
__device__ __forceinline__ h2_t as_h2(unsigned u) {
    h2_t r; __builtin_memcpy(&r, &u, 4); return r;
}
#endif

// ---------------------------------------------------------------------------
// CSR build, bucket-first: no per-edge global atomics anywhere.
// ---------------------------------------------------------------------------

__global__ __launch_bounds__(256) void bucket_hist_kernel(const int* __restrict__ dst,
                                                          int* __restrict__ bcount, int E) {
    __shared__ int lh[NBKT];
    int t = threadIdx.x;
    for (int i = t; i < NBKT; i += 256) lh[i] = 0;
    __syncthreads();
    int base = blockIdx.x * CHUNK_E;
#pragma unroll
    for (int k = 0; k < 16; ++k) {
        int e = base + k * 256 + t;
        if (e < E) atomicAdd(&lh[dst[e] >> BSHIFT], 1);
    }
    __syncthreads();
    for (int i = t; i < NBKT; i += 256) {
        int c = lh[i];
        if (c) atomicAdd(&bcount[i], c);
    }
}

__global__ __launch_bounds__(256) void bucket_scan_kernel(const int* __restrict__ bcount,
                                                          int* __restrict__ bbase,
                                                          int* __restrict__ bfill,
                                                          int* __restrict__ off, int n) {
    __shared__ int sm[256];
    int t = threadIdx.x;
    sm[t] = (t < NBKT) ? bcount[t] : 0;
    __syncthreads();
    for (int d = 1; d < 256; d <<= 1) {
        int v = (t >= d) ? sm[t - d] : 0;
        __syncthreads();
        sm[t] += v;
        __syncthreads();
    }
    if (t < NBKT) {
        int ex = (t == 0) ? 0 : sm[t - 1];
        bbase[t] = ex;
        bfill[t] = ex;
    }
    if (t == 0) {
        bbase[NBKT] = sm[255];       // = E
        off[n] = sm[255];
    }
}

__global__ __launch_bounds__(256) void partition_kernel(const int* __restrict__ src,
                                                        const int* __restrict__ dst,
                                                        int* __restrict__ bfill,
                                                        int* __restrict__ ebuck, int E) {
    __shared__ int lh[NBKT];
    __shared__ int lbase[NBKT];
    int t = threadIdx.x;
    int base = blockIdx.x * CHUNK_E;
    for (int i = t; i < NBKT; i += 256) lh[i] = 0;
    __syncthreads();

    int pk[16], bk[16];
#pragma unroll
    for (int k = 0; k < 16; ++k) {
        int e = base + k * 256 + t;
        if (e < E) {
            int s = src[e];
            int d = dst[e];
            bk[k] = d >> BSHIFT;
            pk[k] = s | ((d & ((1 << BSHIFT) - 1)) << 17);
            atomicAdd(&lh[bk[k]], 1);
        } else {
            bk[k] = -1;
        }
    }
    __syncthreads();
    for (int i = t; i < NBKT; i += 256) {
        int c = lh[i];
        lbase[i] = c ? atomicAdd(&bfill[i], c) : 0;
        lh[i] = 0;
    }
    __syncthreads();
#pragma unroll
    for (int k = 0; k < 16; ++k) {
        if (bk[k] >= 0) {
            int r = atomicAdd(&lh[bk[k]], 1);
            ebuck[lbase[bk[k]] + r] = pk[k];
        }
    }
}

__global__ __launch_bounds__(256) void bucket_csr_kernel(const int* __restrict__ ebuck,
                                                         const int* __restrict__ bbase,
                                                         int* __restrict__ off,
                                                         int* __restrict__ esrc, int n) {
    __shared__ int cnt[512];
    __shared__ int loff[512];
    __shared__ int sm[256];
    int b = blockIdx.x;
    int t = threadIdx.x;
    int ebeg = bbase[b];
    int eend = bbase[b + 1];
    int nbeg = b << BSHIFT;
    int nloc = n - nbeg; if (nloc > 512) nloc = 512;

    cnt[t] = 0; cnt[t + 256] = 0;
    __syncthreads();
    for (int e = ebeg + t; e < eend; e += 256) {
        atomicAdd(&cnt[PK_LD(ebuck[e])], 1);
    }
    __syncthreads();
    int c0 = cnt[2 * t], c1 = cnt[2 * t + 1];
    sm[t] = c0 + c1;
    __syncthreads();
    for (int d = 1; d < 256; d <<= 1) {
        int v = (t >= d) ? sm[t - d] : 0;
        __syncthreads();
        sm[t] += v;
        __syncthreads();
    }
    int basep = (t == 0) ? 0 : sm[t - 1];
    loff[2 * t] = basep;
    loff[2 * t + 1] = basep + c0;
    cnt[2 * t] = 0; cnt[2 * t + 1] = 0;
    __syncthreads();
    for (int i = t; i < nloc; i += 256) off[nbeg + i] = ebeg + loff[i];
    for (int e = ebeg + t; e < eend; e += 256) {
        int v = ebuck[e];
        int d = PK_LD(v);
        int r = atomicAdd(&cnt[d], 1);
        esrc[ebeg + loff[d] + r] = PK_SRC(v);
    }
}

// ---------------------------------------------------------------------------
// Layer-0 GEMM + logits (round-4/5 structure, fp32 x input, fp16 h output).
// ---------------------------------------------------------------------------
template <int FIN, int FINP, int XSTR>
__global__ __launch_bounds__(256) void gemm_tile_kernel(
        const float* __restrict__ act, const float* __restrict__ W,
        const float* __restrict__ a_s, const float* __restrict__ a_d,
        __half* __restrict__ h16g,
        float* __restrict__ ls, float* __restrict__ ld,
        int n) {
    __shared__ float sx[128 * XSTR];
    __shared__ float sw[FINP * 64];
    int t = threadIdx.x;
    int tb = blockIdx.x * 128;
    int nrow = n - tb; if (nrow > 128) nrow = 128;

    {
        const float4* Wv = (const float4*)W;
        float4* swv = (float4*)sw;
        for (int i = t; i < FINP * 16; i += 256) {
            int k = i >> 4;
            swv[i] = (k < FIN) ? Wv[i] : make_float4(0.0f, 0.0f, 0.0f, 0.0f);
        }
    }
    {
        // scalar staging for unaligned FIN-float rows; pad cols [FIN,FINP) to 0
        int c = t & 15;
        for (int r = t >> 4; r < 128; r += 16) {
            float v = 0.0f;
            if (r < nrow && c < FIN) v = act[(size_t)(tb + r) * FIN + c];
            sx[r * XSTR + c] = v;
        }
    }
    __syncthreads();

    int f4 = t & 15;
    int ng = t >> 4;          // [0, 16)

    float4 acc[8];
#pragma unroll
    for (int i = 0; i < 8; ++i) acc[i] = make_float4(0.0f, 0.0f, 0.0f, 0.0f);

    for (int k4 = 0; k4 < FINP; k4 += 4) {
        float4 w0 = *(const float4*)(sw + (k4 + 0) * 64 + f4 * 4);
        float4 w1 = *(const float4*)(sw + (k4 + 1) * 64 + f4 * 4);
        float4 w2 = *(const float4*)(sw + (k4 + 2) * 64 + f4 * 4);
        float4 w3 = *(const float4*)(sw + (k4 + 3) * 64 + f4 * 4);
#pragma unroll
        for (int i = 0; i < 8; ++i) {
            float4 xv = *(const float4*)(sx + (ng + 16 * i) * XSTR + k4);
            acc[i].x = fmaf(xv.x, w0.x, acc[i].x);
            acc[i].y = fmaf(xv.x, w0.y, acc[i].y);
            acc[i].z = fmaf(xv.x, w0.z, acc[i].z);
            acc[i].w = fmaf(xv.x, w0.w, acc[i].w);
            acc[i].x = fmaf(xv.y, w1.x, acc[i].x);
            acc[i].y = fmaf(xv.y, w1.y, acc[i].y);
            acc[i].z = fmaf(xv.y, w1.z, acc[i].z);
            acc[i].w = fmaf(xv.y, w1.w, acc[i].w);
            acc[i].x = fmaf(xv.z, w2.x, acc[i].x);
            acc[i].y = fmaf(xv.z, w2.y, acc[i].y);
            acc[i].z = fmaf(xv.z, w2.z, acc[i].z);
            acc[i].w = fmaf(xv.z, w2.w, acc[i].w);
            acc[i].x = fmaf(xv.w, w3.x, acc[i].x);
            acc[i].y = fmaf(xv.w, w3.y, acc[i].y);
            acc[i].z = fmaf(xv.w, w3.z, acc[i].z);
            acc[i].w = fmaf(xv.w, w3.w, acc[i].w);
        }
    }

    float4 as4 = *(const float4*)(a_s + f4 * 4);
    float4 ad4 = *(const float4*)(a_d + f4 * 4);
#pragma unroll
    for (int i = 0; i < 8; ++i) {
        int r = ng + 16 * i;
        if (r < nrow) {
            int node = tb + r;
            __half2 plo = __floats2half2_rn(acc[i].x, acc[i].y);
            __half2 phi = __floats2half2_rn(acc[i].z, acc[i].w);
            uint2 pk;
            pk.x = *reinterpret_cast<unsigned*>(&plo);
            pk.y = *reinterpret_cast<unsigned*>(&phi);
            *reinterpret_cast<uint2*>(h16g + (size_t)node * 64 + f4 * 4) = pk;
            float vs = acc[i].x * as4.x + acc[i].y * as4.y +
                       acc[i].z * as4.z + acc[i].w * as4.w;
            float vd = acc[i].x * ad4.x + acc[i].y * ad4.y +
                       acc[i].z * ad4.z + acc[i].w * ad4.w;
            vs += __shfl_xor(vs, 1, 64); vd += __shfl_xor(vd, 1, 64);
            vs += __shfl_xor(vs, 2, 64); vd += __shfl_xor(vd, 2, 64);
            vs += __shfl_xor(vs, 4, 64); vd += __shfl_xor(vd, 4, 64);
            vs += __shfl_xor(vs, 8, 64); vd += __shfl_xor(vd, 8, 64);
            if (f4 == 0) { ls[node] = vs; ld[node] = vd; }
        }
    }
}

// ---------------------------------------------------------------------------
// FUSED: gat(layer l) + gemm(layer l+1) + logits(layer l+1).  (round-16 form)
// ---------------------------------------------------------------------------
__global__ __launch_bounds__(256) void gat_gemm_kernel(
        const __half* __restrict__ h16_in, const float* __restrict__ ls_in,
        const float* __restrict__ ld_in, const int* __restrict__ off,
        const int* __restrict__ esrc, const float* __restrict__ bias,
        const float* __restrict__ Wn, const float* __restrict__ asn,
        const float* __restrict__ adn,
        __half* __restrict__ h16_out, float* __restrict__ ls_out,
        float* __restrict__ ld_out, int n) {
#if HAS_FDOT2
    __shared__ unsigned sw2[32 * 64];        // 8 KB: W packed half2 along k
#else
    __shared__ float sw[64 * 64];            // 16 KB: W(l+1) fp32
#endif
    __shared__ int2 smq[16 * DEG_CAP];       // 4 KB: (src, ls->p) per group
    int t = threadIdx.x;
#if HAS_FDOT2
    for (int i = t; i < 32 * 64; i += 256) {
        int k2 = i >> 6, f = i & 63;
        float w0 = Wn[(2 * k2) * 64 + f];
        float w1 = Wn[(2 * k2 + 1) * 64 + f];
        __half2 wp = __floats2half2_rn(w0, w1);
        sw2[i] = *reinterpret_cast<unsigned*>(&wp);
    }
#else
    {
        const float4* Wv = (const float4*)Wn;
        float4* swv = (float4*)sw;
        for (int i = t; i < 64 * 16; i += 256) swv[i] = Wv[i];
    }
#endif
    __syncthreads();   // no barriers after this point (intra-group ops only)

    int fl = t & 15;
    int g = t >> 4;
    int node = blockIdx.x * 16 + g;
    if (node >= n) return;
    int2* sq = smq + g * DEG_CAP;
    int fl4 = fl * 4;
    int sk4 = 4 * g;                          // per-group bank skew

    int jb = off[node];
    int je = off[node + 1];
    int deg = je - jb;
    int degc = (deg < DEG_CAP) ? deg : DEG_CAP;
    float ldv = ld_in[node];
    float lself = ls_in[node];

    // pass 1: gather ls, stage (skewed), running max (leaky is monotone)
    float mm = lself;
    for (int c = fl; c < degc; c += 16) {
        int s = esrc[jb + c];
        float v = ls_in[s];
        sq[(c + sk4) & (DEG_CAP - 1)] = make_int2(s, __float_as_int(v));
        mm = fmaxf(mm, v);
    }
    for (int c = degc + fl; c < deg; c += 16) {
        mm = fmaxf(mm, ls_in[esrc[jb + c]]);
    }
    mm = fmaxf(mm, __shfl_xor(mm, 8, 64));
    mm = fmaxf(mm, __shfl_xor(mm, 4, 64));
    mm = fmaxf(mm, __shfl_xor(mm, 2, 64));
    mm = fmaxf(mm, __shfl_xor(mm, 1, 64));
    float mraw = mm + ldv;
    float m = (mraw >= 0.0f) ? mraw : NEG_SLOPE * mraw;

    // pass 2: ls -> p in LDS, lane-partial den
    float denl = 0.0f;
    for (int c = fl; c < degc; c += 16) {
        int ci = (c + sk4) & (DEG_CAP - 1);
        float e = __int_as_float(sq[ci].y) + ldv;
        e = (e >= 0.0f) ? e : NEG_SLOPE * e;
        float p = __expf(e - m);
        sq[ci].y = __float_as_int(p);
        denl += p;
    }
    int degc4 = (degc + 3) & ~3;
    if (fl < degc4 - degc) sq[(degc + fl + sk4) & (DEG_CAP - 1)] = make_int2(node, 0);

    denl += __shfl_xor(denl, 8, 64);
    denl += __shfl_xor(denl, 4, 64);
    denl += __shfl_xor(denl, 2, 64);
    denl += __shfl_xor(denl, 1, 64);

    // self row early
    uint2 qs = *reinterpret_cast<const uint2*>(h16_in + (size_t)node * 64 + fl4);
    float2 sa = __half22float2(*reinterpret_cast<__half2*>(&qs.x));
    float2 sb = __half22float2(*reinterpret_cast<__half2*>(&qs.y));

    // gather loop: 4 independent 128B fp16 row loads in flight per group
    float4 acc = make_float4(0.0f, 0.0f, 0.0f, 0.0f);
    for (int c = 0; c < degc4; c += 4) {
        int2 e0 = sq[(c + 0 + sk4) & (DEG_CAP - 1)];
        int2 e1 = sq[(c + 1 + sk4) & (DEG_CAP - 1)];
        int2 e2 = sq[(c + 2 + sk4) & (DEG_CAP - 1)];
        int2 e3 = sq[(c + 3 + sk4) & (DEG_CAP - 1)];
        uint2 q0 = *reinterpret_cast<const uint2*>(h16_in + (size_t)e0.x * 64 + fl4);
        uint2 q1 = *reinterpret_cast<const uint2*>(h16_in + (size_t)e1.x * 64 + fl4);
        uint2 q2 = *reinterpret_cast<const uint2*>(h16_in + (size_t)e2.x * 64 + fl4);
        uint2 q3 = *reinterpret_cast<const uint2*>(h16_in + (size_t)e3.x * 64 + fl4);
        float p0 = __int_as_float(e0.y), p1 = __int_as_float(e1.y);
        float p2 = __int_as_float(e2.y), p3 = __int_as_float(e3.y);
        float2 a0 = __half22float2(*reinterpret_cast<__half2*>(&q0.x));
        float2 b0 = __half22float2(*reinterpret_cast<__half2*>(&q0.y));
        float2 a1 = __half22float2(*reinterpret_cast<__half2*>(&q1.x));
        float2 b1 = __half22float2(*reinterpret_cast<__half2*>(&q1.y));
        float2 a2 = __half22float2(*reinterpret_cast<__half2*>(&q2.x));
        float2 b2 = __half22float2(*reinterpret_cast<__half2*>(&q2.y));
        float2 a3 = __half22float2(*reinterpret_cast<__half2*>(&q3.x));
        float2 b3 = __half22float2(*reinterpret_cast<__half2*>(&q3.y));
        acc.x = fmaf(p0, a0.x, acc.x); acc.y = fmaf(p0, a0.y, acc.y);
        acc.z = fmaf(p0, b0.x, acc.z); acc.w = fmaf(p0, b0.y, acc.w);
        acc.x = fmaf(p1, a1.x, acc.x); acc.y = fmaf(p1, a1.y, acc.y);
        acc.z = fmaf(p1, b1.x, acc.z); acc.w = fmaf(p1, b1.y, acc.w);
        acc.x = fmaf(p2, a2.x, acc.x); acc.y = fmaf(p2, a2.y, acc.y);
        acc.z = fmaf(p2, b2.x, acc.z); acc.w = fmaf(p2, b2.y, acc.w);
        acc.x = fmaf(p3, a3.x, acc.x); acc.y = fmaf(p3, a3.y, acc.y);
        acc.z = fmaf(p3, b3.x, acc.z); acc.w = fmaf(p3, b3.y, acc.w);
    }

    // overflow tail (deg > DEG_CAP, ~1e-4 of nodes): exact, reads global
    float den_of = 0.0f;
    for (int j = jb + DEG_CAP; j < je; ++j) {
        int s = esrc[j];
        float e = ls_in[s] + ldv;
        e = (e >= 0.0f) ? e : NEG_SLOPE * e;
        float p = __expf(e - m);
        den_of += p;
        uint2 qv = *reinterpret_cast<const uint2*>(h16_in + (size_t)s * 64 + fl4);
        float2 va = __half22float2(*reinterpret_cast<__half2*>(&qv.x));
        float2 vb = __half22float2(*reinterpret_cast<__half2*>(&qv.y));
        acc.x = fmaf(p, va.x, acc.x);
        acc.y = fmaf(p, va.y, acc.y);
        acc.z = fmaf(p, vb.x, acc.z);
        acc.w = fmaf(p, vb.y, acc.w);
    }

    // self loop
    float e0s = lself + ldv;
    e0s = (e0s >= 0.0f) ? e0s : NEG_SLOPE * e0s;
    float p0s = __expf(e0s - m);
    float den = denl + den_of + p0s;
    acc.x = fmaf(p0s, sa.x, acc.x);
    acc.y = fmaf(p0s, sa.y, acc.y);
    acc.z = fmaf(p0s, sb.x, acc.z);
    acc.w = fmaf(p0s, sb.y, acc.w);

    const float4 b4 = *(const float4*)(bias + fl4);
    float inv = 1.0f / den;
    float4 o;
    o.x = acc.x * inv + b4.x;
    o.y = acc.y * inv + b4.y;
    o.z = acc.z * inv + b4.z;
    o.w = acc.w * inv + b4.w;
    o.x = (o.x > 0.0f) ? o.x : expm1f(o.x);
    o.y = (o.y > 0.0f) ? o.y : expm1f(o.y);
    o.z = (o.z > 0.0f) ? o.z : expm1f(o.z);
    o.w = (o.w > 0.0f) ? o.w : expm1f(o.w);

    // --- fused next-layer GEMM row: hn[f] = sum_k o[k] * Wn[k][f] ---
    float4 ha = make_float4(0.0f, 0.0f, 0.0f, 0.0f);
#if HAS_FDOT2
    {
        __half2 plo = __floats2half2_rn(o.x, o.y);
        __half2 phi = __floats2half2_rn(o.z, o.w);
        uint2 pk;
        pk.x = *reinterpret_cast<unsigned*>(&plo);
        pk.y = *reinterpret_cast<unsigned*>(&phi);
        uint2* so16 = (uint2*)sq;
        so16[(fl + g) & 15] = pk;
#pragma unroll
        for (int kk = 0; kk < 16; ++kk) {
            uint2 ov = so16[(kk + g) & 15];     // o[4kk..4kk+3] as 2x half2
            h2_t o01 = as_h2(ov.x);
            h2_t o23 = as_h2(ov.y);
            const uint4 wA = *reinterpret_cast<const uint4*>(sw2 + (2 * kk) * 64 + fl4);
            const uint4 wB = *reinterpret_cast<const uint4*>(sw2 + (2 * kk + 1) * 64 + fl4);
            ha.x = __builtin_amdgcn_fdot2(o01, as_h2(wA.x), ha.x, false);
            ha.y = __builtin_amdgcn_fdot2(o01, as_h2(wA.y), ha.y, false);
            ha.z = __builtin_amdgcn_fdot2(o01, as_h2(wA.z), ha.z, false);
            ha.w = __builtin_amdgcn_fdot2(o01, as_h2(wA.w), ha.w, false);
            ha.x = __builtin_amdgcn_fdot2(o23, as_h2(wB.x), ha.x, false);
            ha.y = __builtin_amdgcn_fdot2(o23, as_h2(wB.y), ha.y, false);
            ha.z = __builtin_amdgcn_fdot2(o23, as_h2(wB.z), ha.z, false);
            ha.w = __builtin_amdgcn_fdot2(o23, as_h2(wB.w), ha.w, false);
        }
    }
#else
    {
        float4* so = (float4*)sq;
        so[(fl + g) & 15] = o;
#pragma unroll
        for (int kk = 0; kk < 16; ++kk) {
            float4 ov = so[(kk + g) & 15];
            const float4 w0 = *(const float4*)(sw + (4 * kk + 0) * 64 + fl4);
            const float4 w1 = *(const float4*)(sw + (4 * kk + 1) * 64 + fl4);
            const float4 w2 = *(const float4*)(sw + (4 * kk + 2) * 64 + fl4);
            const float4 w3 = *(const float4*)(sw + (4 * kk + 3) * 64 + fl4);
            ha.x = fmaf(ov.x, w0.x, ha.x); ha.y = fmaf(ov.x, w0.y, ha.y);
            ha.z = fmaf(ov.x, w0.z, ha.z); ha.w = fmaf(ov.x, w0.w, ha.w);
            ha.x = fmaf(ov.y, w1.x, ha.x); ha.y = fmaf(ov.y, w1.y, ha.y);
            ha.z = fmaf(ov.y, w1.z, ha.z); ha.w = fmaf(ov.y, w1.w, ha.w);
            ha.x = fmaf(ov.z, w2.x, ha.x); ha.y = fmaf(ov.z, w2.y, ha.y);
            ha.z = fmaf(ov.z, w2.z, ha.z); ha.w = fmaf(ov.z, w2.w, ha.w);
            ha.x = fmaf(ov.w, w3.x, ha.x); ha.y = fmaf(ov.w, w3.y, ha.y);
            ha.z = fmaf(ov.w, w3.z, ha.z); ha.w = fmaf(ov.w, w3.w, ha.w);
        }
    }
#endif

    // store fp16 h row for next layer
    {
        __half2 plo = __floats2half2_rn(ha.x, ha.y);
        __half2 phi = __floats2half2_rn(ha.z, ha.w);
        uint2 pk;
        pk.x = *reinterpret_cast<unsigned*>(&plo);
        pk.y = *reinterpret_cast<unsigned*>(&phi);
        *reinterpret_cast<uint2*>(h16_out + (size_t)node * 64 + fl4) = pk;
    }
    // next-layer logits
    float4 as4 = *(const float4*)(asn + fl4);
    float4 ad4 = *(const float4*)(adn + fl4);
    float vs = ha.x * as4.x + ha.y * as4.y + ha.z * as4.z + ha.w * as4.w;
    float vd = ha.x * ad4.x + ha.y * ad4.y + ha.z * ad4.z + ha.w * ad4.w;
    vs += __shfl_xor(vs, 1, 64); vd += __shfl_xor(vd, 1, 64);
    vs += __shfl_xor(vs, 2, 64); vd += __shfl_xor(vd, 2, 64);
    vs += __shfl_xor(vs, 4, 64); vd += __shfl_xor(vd, 4, 64);
    vs += __shfl_xor(vs, 8, 64); vd += __shfl_xor(vd, 8, 64);
    if (fl == 0) { ls_out[node] = vs; ld_out[node] = vd; }
}

// ---------------------------------------------------------------------------
// Final-layer GAT fused with global max pool: computes the fp32 activation o
// per node, stages it in LDS, then one wave per block run-length-reduces the
// block's 16 nodes (batch sorted => <=2 graph runs) and atomicMax's into the
// encoded per-graph maxima. No 25.6MB h_a materialize + re-read.
// ---------------------------------------------------------------------------
__device__ __forceinline__ unsigned enc_f32(float f) {
    unsigned b = __float_as_uint(f);
    return (b & 0x80000000u) ? ~b : (b | 0x80000000u);
}

__global__ __launch_bounds__(256) void gat_final_pool_kernel(
        const __half* __restrict__ h16_in,
        const float* __restrict__ ls_in,
        const float* __restrict__ ld_in, const int* __restrict__ off,
        const int* __restrict__ esrc, const float* __restrict__ bias,
        const int* __restrict__ batch, unsigned* __restrict__ genc, int n) {
    __shared__ int2 smq[16 * DEG_CAP];       // 4 KB
    __shared__ float sbo[16 * 64];           // 4 KB: per-node activation
    __shared__ int sbb[16];                  // per-node graph id
    int t = threadIdx.x;
    int fl = t & 15;
    int g = t >> 4;
    int node = blockIdx.x * 16 + g;
    bool active = node < n;
    int2* sq = smq + g * DEG_CAP;
    int fl4 = fl * 4;
    int sk4 = 4 * g;

    if (active) {
        int jb = off[node];
        int je = off[node + 1];
        int deg = je - jb;
        int degc = (deg < DEG_CAP) ? deg : DEG_CAP;
        float ldv = ld_in[node];
        float lself = ls_in[node];

        float mm = lself;
        for (int c = fl; c < degc; c += 16) {
            int s = esrc[jb + c];
            float v = ls_in[s];
            sq[(c + sk4) & (DEG_CAP - 1)] = make_int2(s, __float_as_int(v));
            mm = fmaxf(mm, v);
        }
        for (int c = degc + fl; c < deg; c += 16) {
            mm = fmaxf(mm, ls_in[esrc[jb + c]]);
        }
        mm = fmaxf(mm, __shfl_xor(mm, 8, 64));
        mm = fmaxf(mm, __shfl_xor(mm, 4, 64));
        mm = fmaxf(mm, __shfl_xor(mm, 2, 64));
        mm = fmaxf(mm, __shfl_xor(mm, 1, 64));
        float mraw = mm + ldv;
        float m = (mraw >= 0.0f) ? mraw : NEG_SLOPE * mraw;

        float denl = 0.0f;
        for (int c = fl; c < degc; c += 16) {
            int ci = (c + sk4) & (DEG_CAP - 1);
            float e = __int_as_float(sq[ci].y) + ldv;
            e = (e >= 0.0f) ? e : NEG_SLOPE * e;
            float p = __expf(e - m);
            sq[ci].y = __float_as_int(p);
            denl += p;
        }
        int degc4 = (degc + 3) & ~3;
        if (fl < degc4 - degc) sq[(degc + fl + sk4) & (DEG_CAP - 1)] = make_int2(node, 0);

        denl += __shfl_xor(denl, 8, 64);
        denl += __shfl_xor(denl, 4, 64);
        denl += __shfl_xor(denl, 2, 64);
        denl += __shfl_xor(denl, 1, 64);

        uint2 qs = *reinterpret_cast<const uint2*>(h16_in + (size_t)node * 64 + fl4);
        float2 sa = __half22float2(*reinterpret_cast<__half2*>(&qs.x));
        float2 sb = __half22float2(*reinterpret_cast<__half2*>(&qs.y));

        float4 acc = make_float4(0.0f, 0.0f, 0.0f, 0.0f);
        for (int c = 0; c < degc4; c += 4) {
            int2 e0 = sq[(c + 0 + sk4) & (DEG_CAP - 1)];
            int2 e1 = sq[(c + 1 + sk4) & (DEG_CAP - 1)];
            int2 e2 = sq[(c + 2 + sk4) & (DEG_CAP - 1)];
            int2 e3 = sq[(c + 3 + sk4) & (DEG_CAP - 1)];
            uint2 q0 = *reinterpret_cast<const uint2*>(h16_in + (size_t)e0.x * 64 + fl4);
            uint2 q1 = *reinterpret_cast<const uint2*>(h16_in + (size_t)e1.x * 64 + fl4);
            uint2 q2 = *reinterpret_cast<const uint2*>(h16_in + (size_t)e2.x * 64 + fl4);
            uint2 q3 = *reinterpret_cast<const uint2*>(h16_in + (size_t)e3.x * 64 + fl4);
            float p0 = __int_as_float(e0.y), p1 = __int_as_float(e1.y);
            float p2 = __int_as_float(e2.y), p3 = __int_as_float(e3.y);
            float2 a0 = __half22float2(*reinterpret_cast<__half2*>(&q0.x));
            float2 b0 = __half22float2(*reinterpret_cast<__half2*>(&q0.y));
            float2 a1 = __half22float2(*reinterpret_cast<__half2*>(&q1.x));
            float2 b1 = __half22float2(*reinterpret_cast<__half2*>(&q1.y));
            float2 a2 = __half22float2(*reinterpret_cast<__half2*>(&q2.x));
            float2 b2 = __half22float2(*reinterpret_cast<__half2*>(&q2.y));
            float2 a3 = __half22float2(*reinterpret_cast<__half2*>(&q3.x));
            float2 b3 = __half22float2(*reinterpret_cast<__half2*>(&q3.y));
            acc.x = fmaf(p0, a0.x, acc.x); acc.y = fmaf(p0, a0.y, acc.y);
            acc.z = fmaf(p0, b0.x, acc.z); acc.w = fmaf(p0, b0.y, acc.w);
            acc.x = fmaf(p1, a1.x, acc.x); acc.y = fmaf(p1, a1.y, acc.y);
            acc.z = fmaf(p1, b1.x, acc.z); acc.w = fmaf(p1, b1.y, acc.w);
            acc.x = fmaf(p2, a2.x, acc.x); acc.y = fmaf(p2, a2.y, acc.y);
            acc.z = fmaf(p2, b2.x, acc.z); acc.w = fmaf(p2, b2.y, acc.w);
            acc.x = fmaf(p3, a3.x, acc.x); acc.y = fmaf(p3, a3.y, acc.y);
            acc.z = fmaf(p3, b3.x, acc.z); acc.w = fmaf(p3, b3.y, acc.w);
        }

        float den_of = 0.0f;
        for (int j = jb + DEG_CAP; j < je; ++j) {
            int s = esrc[j];
            float e = ls_in[s] + ldv;
            e = (e >= 0.0f) ? e : NEG_SLOPE * e;
            float p = __expf(e - m);
            den_of += p;
            uint2 qv = *reinterpret_cast<const uint2*>(h16_in + (size_t)s * 64 + fl4);
            float2 va = __half22float2(*reinterpret_cast<__half2*>(&qv.x));
            float2 vb = __half22float2(*reinterpret_cast<__half2*>(&qv.y));
            acc.x = fmaf(p, va.x, acc.x);
            acc.y = fmaf(p, va.y, acc.y);
            acc.z = fmaf(p, vb.x, acc.z);
            acc.w = fmaf(p, vb.y, acc.w);
        }

        float e0s = lself + ldv;
        e0s = (e0s >= 0.0f) ? e0s : NEG_SLOPE * e0s;
        float p0s = __expf(e0s - m);
        float den = denl + den_of + p0s;
        acc.x = fmaf(p0s, sa.x, acc.x);
        acc.y = fmaf(p0s, sa.y, acc.y);
        acc.z = fmaf(p0s, sb.x, acc.z);
        acc.w = fmaf(p0s, sb.y, acc.w);

        const float4 b4 = *(const float4*)(bias + fl4);
        float inv = 1.0f / den;
        float4 o;
        o.x = acc.x * inv + b4.x;
        o.y = acc.y * inv + b4.y;
        o.z = acc.z * inv + b4.z;
        o.w = acc.w * inv + b4.w;
        o.x = (o.x > 0.0f) ? o.x : expm1f(o.x);
        o.y = (o.y > 0.0f) ? o.y : expm1f(o.y);
        o.z = (o.z > 0.0f) ? o.z : expm1f(o.z);
        o.w = (o.w > 0.0f) ? o.w : expm1f(o.w);

        *(float4*)(sbo + g * 64 + fl4) = o;
        if (fl == 0) sbb[g] = batch[node];
    }
    __syncthreads();

    // one wave run-length-reduces the block's nodes into genc
    if (t < 64) {
        int nval = n - blockIdx.x * 16;
        if (nval > 16) nval = 16;
        if (nval > 0) {
            int cur = sbb[0];
            float rm = -1e38f;
            for (int gg = 0; gg < nval; ++gg) {
                int b = sbb[gg];                     // wave-uniform
                if (b != cur) {
                    atomicMax(&genc[cur * 64 + t], enc_f32(rm));
                    cur = b;
                    rm = -1e38f;
                }
                rm = fmaxf(rm, sbo[gg * 64 + t]);
            }
            atomicMax(&genc[cur * 64 + t], enc_f32(rm));
        }
    }
}

__global__ __launch_bounds__(64) void final_kernel(const unsigned* __restrict__ genc,
                                                   const float* __restrict__ linW,
                                                   const float* __restrict__ linb,
                                                   float* __restrict__ out) {
    int g = blockIdx.x;
    int lane = threadIdx.x;
    unsigned u = genc[g * 64 + lane];
    float v;
    if (u == 0u) {
        v = 0.0f;
    } else {
        unsigned b = (u & 0x80000000u) ? (u ^ 0x80000000u) : ~u;
        v = __uint_as_float(b);
    }
    float c0 = v * linW[lane * 2 + 0];
    float c1 = v * linW[lane * 2 + 1];
#pragma unroll
    for (int d = 32; d >= 1; d >>= 1) {
        c0 += __shfl_xor(c0, d, 64);
        c1 += __shfl_xor(c1, d, 64);
    }
    if (lane == 0) {
        out[g * 2 + 0] = c0 + linb[0];
        out[g * 2 + 1] = c1 + linb[1];
    }
}

// ---------------------------------------------------------------------------
// Launch
// ---------------------------------------------------------------------------
static inline size_t align_up(size_t v, size_t a) { return (v + a - 1) & ~(a - 1); }

extern "C" void kernel_launch(void* const* d_in, const int* in_sizes, int n_in,
                              void* d_out, int out_size, void* d_ws, size_t ws_size,
                              hipStream_t stream) {
    const float* x          = (const float*)d_in[0];
    const int*   edge_index = (const int*)d_in[1];
    const int*   batch      = (const int*)d_in[2];
    const float* W[5];
    const float* a_s[5];
    const float* a_d[5];
    const float* bias[5];
    for (int l = 0; l < 5; ++l) {
        W[l]    = (const float*)d_in[3 + 4 * l + 0];
        a_s[l]  = (const float*)d_in[3 + 4 * l + 1];
        a_d[l]  = (const float*)d_in[3 + 4 * l + 2];
        bias[l] = (const float*)d_in[3 + 4 * l + 3];
    }
    const float* linW = (const float*)d_in[23];
    const float* linb = (const float*)d_in[24];
    float* out = (float*)d_out;

    const int N = N_NODES;
    const int E = in_sizes[1] / 2;
    const int* srcp = edge_index;
    const int* dstp = edge_index + E;

    // workspace partition
    char* p = (char*)d_ws;
    int* bcount = (int*)p;        p += align_up((size_t)NBKT * 4, 256);
    int* bbase  = (int*)p;        p += align_up((size_t)(NBKT + 1) * 4, 256);
    int* bfill  = (int*)p;        p += align_up((size_t)NBKT * 4, 256);
    int* off    = (int*)p;        p += align_up((size_t)(N + 1) * 4, 256);
    int* esrc   = (int*)p;        p += align_up((size_t)E * 4, 256);
    float* lsA  = (float*)p;      p += align_up((size_t)N * 4, 256);
    float* ldA  = (float*)p;      p += align_up((size_t)N * 4, 256);
    float* lsB  = (float*)p;      p += align_up((size_t)N * 4, 256);
    float* ldB  = (float*)p;      p += align_up((size_t)N * 4, 256);
    __half* h16A = (__half*)p;    p += align_up((size_t)N * 64 * 2, 256);
    __half* h16B = (__half*)p;    p += align_up((size_t)N * 64 * 2, 256);
    unsigned* genc = (unsigned*)p; p += align_up((size_t)G_GRAPHS * 64 * 4, 256);

    // ebuck (E ints, 6.4MB, packed) aliases h16B (12.8MB): fully consumed by
    // bucket_csr before the first gat_gemm writes h16B.
    int* ebuck = (int*)h16B;

    hipMemsetAsync(bcount, 0, (size_t)NBKT * 4, stream);
    hipMemsetAsync(genc, 0, (size_t)G_GRAPHS * 64 * 4, stream);

    int pb2 = (E + CHUNK_E - 1) / CHUNK_E;
    bucket_hist_kernel<<<pb2, 256, 0, stream>>>(dstp, bcount, E);
    bucket_scan_kernel<<<1, 256, 0, stream>>>(bcount, bbase, bfill, off, N);
    partition_kernel<<<pb2, 256, 0, stream>>>(srcp, dstp, bfill, ebuck, E);
    bucket_csr_kernel<<<NBKT, 256, 0, stream>>>(ebuck, bbase, off, esrc, N);

    int nb = (N + 15) / 16;   // 16 nodes per block
    int gt = (N + 127) / 128; // layer-0 GEMM: 128-node tiles

    // layer-0 GEMM -> set A
    gemm_tile_kernel<14, 16, 20><<<gt, 256, 0, stream>>>(
        x, W[0], a_s[0], a_d[0], h16A, lsA, ldA, N);
    // fused gat(l) + gemm(l+1), alternating buffers A->B->A->B->A
    gat_gemm_kernel<<<nb, 256, 0, stream>>>(
        h16A, lsA, ldA, off, esrc, bias[0], W[1], a_s[1], a_d[1],
        h16B, lsB, ldB, N);
    gat_gemm_kernel<<<nb, 256, 0, stream>>>(
        h16B, lsB, ldB, off, esrc, bias[1], W[2], a_s[2], a_d[2],
        h16A, lsA, ldA, N);
    gat_gemm_kernel<<<nb, 256, 0, stream>>>(
        h16A, lsA, ldA, off, esrc, bias[2], W[3], a_s[3], a_d[3],
        h16B, lsB, ldB, N);
    gat_gemm_kernel<<<nb, 256, 0, stream>>>(
        h16B, lsB, ldB, off, esrc, bias[3], W[4], a_s[4], a_d[4],
        h16A, lsA, ldA, N);
    // final layer: gat fused with global max pool (no h_a materialize)
    gat_final_pool_kernel<<<nb, 256, 0, stream>>>(
        h16A, lsA, ldA, off, esrc, bias[4], batch, genc, N);

    final_kernel<<<G_GRAPHS, 64, 0, stream>>>(genc, linW, linb, out);
}